// Round 1
// baseline (255.381 us; speedup 1.0000x reference)
//
#include <hip/hip_runtime.h>

#define NW 3
#define NF 48
#define NHOST 16
#define NLAT 10
#define GOUT 16
#define EDIM 19
#define PDIM 10

__device__ __forceinline__ float frcp(float x) { return __builtin_amdgcn_rcpf(x); }
__device__ __forceinline__ float fsig(float x) { return frcp(1.0f + __expf(-x)); }
__device__ __forceinline__ float ftanh(float x) { return 1.0f - 2.0f * frcp(1.0f + __expf(2.0f * x)); }

// ---------------- K1: GRU + GAT + MHA -> flat[57][B] ----------------
__global__ __launch_bounds__(256) void k_front(
    const float* __restrict__ t, const float* __restrict__ h0,
    const float* __restrict__ Wih, const float* __restrict__ Whh,
    const float* __restrict__ bih, const float* __restrict__ bhh,
    const float* __restrict__ gatW, const float* __restrict__ gal, const float* __restrict__ gar,
    const float* __restrict__ Win, const float* __restrict__ bin,
    const float* __restrict__ Wout, const float* __restrict__ bout,
    float* __restrict__ flat, int B)
{
    const int b = blockIdx.x * blockDim.x + threadIdx.x;
    if (b >= B) return;

    // GRU state
    float h[3] = { h0[b*3+0], h0[b*3+1], h0[b*3+2] };

    // Wal = gat_W @ gat_al, War = gat_W @ gat_ar  (uniform, 96 MACs)
    float Wal[3], War[3];
#pragma unroll
    for (int c = 0; c < 3; ++c) {
        float a = 0.f, r = 0.f;
#pragma unroll
        for (int f = 0; f < GOUT; ++f) { a += gatW[c*GOUT+f]*gal[f]; r += gatW[c*GOUT+f]*gar[f]; }
        Wal[c] = a; War[c] = r;
    }

    float cw[NW][EDIM];
    const float* trow = t + (size_t)b * (NW*NF);

#pragma unroll
    for (int w = 0; w < NW; ++w) {
        // load this window's 48 features
        float x[NF];
#pragma unroll
        for (int i = 0; i < NF/4; ++i) {
            float4 v4 = *reinterpret_cast<const float4*>(trow + w*NF + i*4);
            x[i*4+0] = v4.x; x[i*4+1] = v4.y; x[i*4+2] = v4.z; x[i*4+3] = v4.w;
        }
        // ---- GRU step ----
        float gi[9];
#pragma unroll
        for (int r = 0; r < 9; ++r) {
            float acc = bih[r];
#pragma unroll
            for (int j = 0; j < NF; ++j) acc += x[j] * Wih[r*NF + j];
            gi[r] = acc;
        }
        float gh[9];
#pragma unroll
        for (int r = 0; r < 9; ++r)
            gh[r] = bhh[r] + h[0]*Whh[r*3+0] + h[1]*Whh[r*3+1] + h[2]*Whh[r*3+2];
#pragma unroll
        for (int j = 0; j < 3; ++j) {
            float rg = fsig(gi[j]   + gh[j]);
            float zg = fsig(gi[3+j] + gh[3+j]);
            float ng = ftanh(gi[6+j] + rg * gh[6+j]);
            h[j] = (1.0f - zg) * ng + zg * h[j];
        }
        cw[w][0] = h[0]; cw[w][1] = h[1]; cw[w][2] = h[2];

        // ---- GAT (collapsed) ----
        float el[NHOST], er[NHOST];
#pragma unroll
        for (int n = 0; n < NHOST; ++n) {
            el[n] = x[n*3+0]*Wal[0] + x[n*3+1]*Wal[1] + x[n*3+2]*Wal[2];
            er[n] = x[n*3+0]*War[0] + x[n*3+1]*War[1] + x[n*3+2]*War[2];
        }
        float beta[NHOST];
#pragma unroll
        for (int u = 0; u < NHOST; ++u) beta[u] = 0.f;
#pragma unroll
        for (int v = 0; v < NHOST; ++v) {
            float ee[NHOST]; float m = -1e30f;
#pragma unroll
            for (int u = 0; u < NHOST; ++u) {
                float s = er[v] + el[u];
                s = s > 0.f ? s : 0.2f * s;
                ee[u] = s; m = fmaxf(m, s);
            }
            float sum = 0.f;
#pragma unroll
            for (int u = 0; u < NHOST; ++u) { ee[u] = __expf(ee[u] - m); sum += ee[u]; }
            float inv = frcp(sum);
#pragma unroll
            for (int u = 0; u < NHOST; ++u) beta[u] += ee[u] * inv;
        }
        float g0 = 0.f, g1 = 0.f, g2 = 0.f;
#pragma unroll
        for (int u = 0; u < NHOST; ++u) {
            float bu = beta[u] * (1.0f/16.0f);
            g0 += bu * x[u*3+0]; g1 += bu * x[u*3+1]; g2 += bu * x[u*3+2];
        }
#pragma unroll
        for (int f = 0; f < GOUT; ++f)
            cw[w][3+f] = g0*gatW[0*GOUT+f] + g1*gatW[1*GOUT+f] + g2*gatW[2*GOUT+f];
    }

    // ---- MHA ----
    float q[NW][EDIM];
#pragma unroll
    for (int w = 0; w < NW; ++w) {
#pragma unroll
        for (int e = 0; e < EDIM; ++e) {
            float a = bin[e];
#pragma unroll
            for (int j = 0; j < EDIM; ++j) a += cw[w][j] * Win[e*EDIM + j];
            q[w][e] = a;
        }
    }
    float sc[NW][NW];
#pragma unroll
    for (int tt = 0; tt < NW; ++tt) {
        float kt[EDIM];
#pragma unroll
        for (int e = 0; e < EDIM; ++e) {
            float a = bin[EDIM + e];
#pragma unroll
            for (int j = 0; j < EDIM; ++j) a += cw[tt][j] * Win[(EDIM+e)*EDIM + j];
            kt[e] = a;
        }
#pragma unroll
        for (int s = 0; s < NW; ++s) {
            float a = 0.f;
#pragma unroll
            for (int e = 0; e < EDIM; ++e) a += q[s][e] * kt[e];
            sc[s][tt] = a * 0.2294157338705618f; // 1/sqrt(19)
        }
    }
    float attw[NW][NW];
#pragma unroll
    for (int s = 0; s < NW; ++s) {
        float m = fmaxf(sc[s][0], fmaxf(sc[s][1], sc[s][2]));
        float e0 = __expf(sc[s][0]-m), e1 = __expf(sc[s][1]-m), e2 = __expf(sc[s][2]-m);
        float inv = frcp(e0 + e1 + e2);
        attw[s][0] = e0*inv; attw[s][1] = e1*inv; attw[s][2] = e2*inv;
    }
    float ar[NW][EDIM];
#pragma unroll
    for (int s = 0; s < NW; ++s)
#pragma unroll
        for (int e = 0; e < EDIM; ++e) ar[s][e] = 0.f;
#pragma unroll
    for (int tt = 0; tt < NW; ++tt) {
        float vt[EDIM];
#pragma unroll
        for (int e = 0; e < EDIM; ++e) {
            float a = bin[2*EDIM + e];
#pragma unroll
            for (int j = 0; j < EDIM; ++j) a += cw[tt][j] * Win[(2*EDIM+e)*EDIM + j];
            vt[e] = a;
        }
#pragma unroll
        for (int s = 0; s < NW; ++s)
#pragma unroll
            for (int e = 0; e < EDIM; ++e) ar[s][e] += attw[s][tt] * vt[e];
    }
    // out-proj, write flat transposed [j][B]
#pragma unroll
    for (int s = 0; s < NW; ++s) {
#pragma unroll
        for (int e = 0; e < EDIM; ++e) {
            float a = bout[e];
#pragma unroll
            for (int j = 0; j < EDIM; ++j) a += ar[s][j] * Wout[e*EDIM + j];
            flat[(s*EDIM + e) * (size_t)B + b] = a;
        }
    }
}

// ---------------- K2: encoder + heads ----------------
__global__ __launch_bounds__(256) void k_back(
    const float* __restrict__ flat,
    const float* __restrict__ encW, const float* __restrict__ encb,
    const float* __restrict__ aW, const float* __restrict__ ab,
    const float* __restrict__ pW, const float* __restrict__ pb,
    float* __restrict__ outA, float* __restrict__ outP, int B)
{
    const int tid = blockIdx.x * blockDim.x + threadIdx.x;
    const int b = tid >> 4;
    const int hh = tid & 15;
    if (b >= B) return;

    float f[57];
#pragma unroll
    for (int j = 0; j < 57; ++j) f[j] = flat[(size_t)j * B + b];

    float lat[NLAT];
#pragma unroll
    for (int l = 0; l < NLAT; ++l) {
        const int row = hh * NLAT + l;
        float a = encb[row];
#pragma unroll
        for (int j = 0; j < 57; ++j) a += f[j] * encW[row*57 + j];
        lat[l] = a;
    }

    // anomaly head: 2-class softmax
    float a0 = ab[0], a1 = ab[1];
#pragma unroll
    for (int l = 0; l < NLAT; ++l) { a0 += lat[l]*aW[l]; a1 += lat[l]*aW[NLAT+l]; }
    float m = fmaxf(a0, a1);
    float e0 = __expf(a0 - m), e1 = __expf(a1 - m);
    float inv = frcp(e0 + e1);
    outA[(size_t)b*32 + hh*2 + 0] = e0 * inv;
    outA[(size_t)b*32 + hh*2 + 1] = e1 * inv;

    // proto head: sigmoid
#pragma unroll
    for (int p = 0; p < PDIM; ++p) {
        float a = pb[p];
#pragma unroll
        for (int l = 0; l < NLAT; ++l) a += lat[l] * pW[p*NLAT + l];
        outP[(size_t)b*160 + hh*10 + p] = fsig(a);
    }
}

extern "C" void kernel_launch(void* const* d_in, const int* in_sizes, int n_in,
                              void* d_out, int out_size, void* d_ws, size_t ws_size,
                              hipStream_t stream) {
    const float* t    = (const float*)d_in[0];
    const float* h0   = (const float*)d_in[2];
    const float* Wih  = (const float*)d_in[3];
    const float* Whh  = (const float*)d_in[4];
    const float* bih  = (const float*)d_in[5];
    const float* bhh  = (const float*)d_in[6];
    const float* gatW = (const float*)d_in[7];
    const float* gal  = (const float*)d_in[8];
    const float* gar  = (const float*)d_in[9];
    const float* Win  = (const float*)d_in[10];
    const float* bin  = (const float*)d_in[11];
    const float* Wout = (const float*)d_in[12];
    const float* bout = (const float*)d_in[13];
    const float* encW = (const float*)d_in[14];
    const float* encb = (const float*)d_in[15];
    const float* aW   = (const float*)d_in[16];
    const float* ab   = (const float*)d_in[17];
    const float* pW   = (const float*)d_in[18];
    const float* pb   = (const float*)d_in[19];

    const int B = in_sizes[0] / (NW * NF);
    float* flat = (float*)d_ws;
    float* outA = (float*)d_out;
    float* outP = (float*)d_out + (size_t)B * 32;

    k_front<<<dim3((B + 255) / 256), dim3(256), 0, stream>>>(
        t, h0, Wih, Whh, bih, bhh, gatW, gal, gar, Win, bin, Wout, bout, flat, B);
    k_back<<<dim3((B * 16 + 255) / 256), dim3(256), 0, stream>>>(
        flat, encW, encb, aW, ab, pW, pb, outA, outP, B);
}

// Round 2
// 191.423 us; speedup vs baseline: 1.3341x; 1.3341x over previous
//
#include <hip/hip_runtime.h>

#define NW 3
#define NF 48
#define NHOST 16
#define NLAT 10
#define GOUT 16
#define EDIM 19
#define PDIM 10

__device__ __forceinline__ float frcp(float x) { return __builtin_amdgcn_rcpf(x); }
__device__ __forceinline__ float fsig(float x) { return frcp(1.0f + __expf(-x)); }
__device__ __forceinline__ float ftanh(float x) { return 1.0f - 2.0f * frcp(1.0f + __expf(2.0f * x)); }

// One thread per batch element: GRU + GAT + MHA + encoder + heads, fully fused.
// Grid = 1024 waves = 1 wave/SIMD -> occupancy is grid-limited; VGPRs are free.
// All weight reads have wave-uniform addresses -> scalar (s_load) path.
__global__ __launch_bounds__(256, 1) void k_fused(
    const float* __restrict__ t, const float* __restrict__ h0,
    const float* __restrict__ Wih, const float* __restrict__ Whh,
    const float* __restrict__ bih, const float* __restrict__ bhh,
    const float* __restrict__ gatW, const float* __restrict__ gal, const float* __restrict__ gar,
    const float* __restrict__ Win, const float* __restrict__ bin,
    const float* __restrict__ Wout, const float* __restrict__ bout,
    const float* __restrict__ encW, const float* __restrict__ encb,
    const float* __restrict__ aW, const float* __restrict__ ab,
    const float* __restrict__ pW, const float* __restrict__ pb,
    float* __restrict__ outA, float* __restrict__ outP, int B)
{
    const int b = blockIdx.x * blockDim.x + threadIdx.x;
    if (b >= B) return;

    // GRU state
    float h[3] = { h0[b*3+0], h0[b*3+1], h0[b*3+2] };

    // Wal = gat_W @ gat_al, War = gat_W @ gat_ar (uniform, tiny)
    float Wal[3], War[3];
#pragma unroll
    for (int c = 0; c < 3; ++c) {
        float a = 0.f, r = 0.f;
#pragma unroll
        for (int f = 0; f < GOUT; ++f) { a += gatW[c*GOUT+f]*gal[f]; r += gatW[c*GOUT+f]*gar[f]; }
        Wal[c] = a; War[c] = r;
    }

    float cw[NW][EDIM];
    const float* trow = t + (size_t)b * (NW*NF);

#pragma unroll
    for (int w = 0; w < NW; ++w) {
        float x[NF];
#pragma unroll
        for (int i = 0; i < NF/4; ++i) {
            float4 v4 = *reinterpret_cast<const float4*>(trow + w*NF + i*4);
            x[i*4+0] = v4.x; x[i*4+1] = v4.y; x[i*4+2] = v4.z; x[i*4+3] = v4.w;
        }
        // ---- GRU step ----
        float gi[9];
#pragma unroll
        for (int r = 0; r < 9; ++r) {
            float acc = bih[r];
#pragma unroll
            for (int j = 0; j < NF; ++j) acc += x[j] * Wih[r*NF + j];
            gi[r] = acc;
        }
#pragma unroll
        for (int j = 0; j < 3; ++j) {
            float ghr = bhh[j]   + h[0]*Whh[j*3+0]     + h[1]*Whh[j*3+1]     + h[2]*Whh[j*3+2];
            float ghz = bhh[3+j] + h[0]*Whh[(3+j)*3+0] + h[1]*Whh[(3+j)*3+1] + h[2]*Whh[(3+j)*3+2];
            float ghn = bhh[6+j] + h[0]*Whh[(6+j)*3+0] + h[1]*Whh[(6+j)*3+1] + h[2]*Whh[(6+j)*3+2];
            float rg = fsig(gi[j]   + ghr);
            float zg = fsig(gi[3+j] + ghz);
            float ng = ftanh(gi[6+j] + rg * ghn);
            h[j] = (1.0f - zg) * ng + zg * h[j];
        }
        // careful: all three gates must use pre-update h; compute with temp
        // (loop above uses h[j] only in its own lane j for state update, but
        //  ghr/ghz/ghn use h[0..2]; j=0 updates h[0] before j=1 reads it.)
        cw[w][0] = h[0]; cw[w][1] = h[1]; cw[w][2] = h[2];

        // ---- GAT (collapsed: gat_out = (sum_u beta_u * gin_u) @ W) ----
        float el[NHOST], er[NHOST];
#pragma unroll
        for (int n = 0; n < NHOST; ++n) {
            el[n] = x[n*3+0]*Wal[0] + x[n*3+1]*Wal[1] + x[n*3+2]*Wal[2];
            er[n] = x[n*3+0]*War[0] + x[n*3+1]*War[1] + x[n*3+2]*War[2];
        }
        float beta[NHOST];
#pragma unroll
        for (int u = 0; u < NHOST; ++u) beta[u] = 0.f;
#pragma unroll
        for (int v = 0; v < NHOST; ++v) {
            float ee[NHOST]; float sum = 0.f;
#pragma unroll
            for (int u = 0; u < NHOST; ++u) {
                float s = er[v] + el[u];
                s = fmaxf(s, 0.2f * s);          // leaky_relu; bounded ~|3|, exp safe
                ee[u] = __expf(s); sum += ee[u];
            }
            float inv = frcp(sum);
#pragma unroll
            for (int u = 0; u < NHOST; ++u) beta[u] += ee[u] * inv;
        }
        float g0 = 0.f, g1 = 0.f, g2 = 0.f;
#pragma unroll
        for (int u = 0; u < NHOST; ++u) {
            float bu = beta[u] * (1.0f/16.0f);
            g0 += bu * x[u*3+0]; g1 += bu * x[u*3+1]; g2 += bu * x[u*3+2];
        }
#pragma unroll
        for (int f = 0; f < GOUT; ++f)
            cw[w][3+f] = g0*gatW[0*GOUT+f] + g1*gatW[1*GOUT+f] + g2*gatW[2*GOUT+f];
    }

    // ---- MHA ----
    float q[NW][EDIM];
#pragma unroll
    for (int w = 0; w < NW; ++w) {
#pragma unroll
        for (int e = 0; e < EDIM; ++e) {
            float a = bin[e];
#pragma unroll
            for (int j = 0; j < EDIM; ++j) a += cw[w][j] * Win[e*EDIM + j];
            q[w][e] = a;
        }
    }
    float sc[NW][NW];
#pragma unroll
    for (int tt = 0; tt < NW; ++tt) {
        float kt[EDIM];
#pragma unroll
        for (int e = 0; e < EDIM; ++e) {
            float a = bin[EDIM + e];
#pragma unroll
            for (int j = 0; j < EDIM; ++j) a += cw[tt][j] * Win[(EDIM+e)*EDIM + j];
            kt[e] = a;
        }
#pragma unroll
        for (int s = 0; s < NW; ++s) {
            float a = 0.f;
#pragma unroll
            for (int e = 0; e < EDIM; ++e) a += q[s][e] * kt[e];
            sc[s][tt] = a * 0.2294157338705618f; // 1/sqrt(19)
        }
    }
    float attw[NW][NW];
#pragma unroll
    for (int s = 0; s < NW; ++s) {
        float m = fmaxf(sc[s][0], fmaxf(sc[s][1], sc[s][2]));
        float e0 = __expf(sc[s][0]-m), e1 = __expf(sc[s][1]-m), e2 = __expf(sc[s][2]-m);
        float inv = frcp(e0 + e1 + e2);
        attw[s][0] = e0*inv; attw[s][1] = e1*inv; attw[s][2] = e2*inv;
    }
    float f[NW*EDIM]; // flat, via attn accumulation + out-proj
    float ar[NW][EDIM];
#pragma unroll
    for (int s = 0; s < NW; ++s)
#pragma unroll
        for (int e = 0; e < EDIM; ++e) ar[s][e] = 0.f;
#pragma unroll
    for (int tt = 0; tt < NW; ++tt) {
        float vt[EDIM];
#pragma unroll
        for (int e = 0; e < EDIM; ++e) {
            float a = bin[2*EDIM + e];
#pragma unroll
            for (int j = 0; j < EDIM; ++j) a += cw[tt][j] * Win[(2*EDIM+e)*EDIM + j];
            vt[e] = a;
        }
#pragma unroll
        for (int s = 0; s < NW; ++s)
#pragma unroll
            for (int e = 0; e < EDIM; ++e) ar[s][e] += attw[s][tt] * vt[e];
    }
#pragma unroll
    for (int s = 0; s < NW; ++s) {
#pragma unroll
        for (int e = 0; e < EDIM; ++e) {
            float a = bout[e];
#pragma unroll
            for (int j = 0; j < EDIM; ++j) a += ar[s][j] * Wout[e*EDIM + j];
            f[s*EDIM + e] = a;
        }
    }

    // ---- encoder + heads, per host; weight addresses wave-uniform -> s_load ----
    float* pA = outA + (size_t)b * 32;
    float* pP = outP + (size_t)b * 160;
#pragma unroll 1
    for (int hh = 0; hh < NHOST; ++hh) {
        float lat[NLAT];
#pragma unroll
        for (int l = 0; l < NLAT; ++l) {
            const int row = hh * NLAT + l;
            float a = encb[row];
#pragma unroll
            for (int j = 0; j < 57; ++j) a += f[j] * encW[row*57 + j];
            lat[l] = a;
        }
        // anomaly: 2-class softmax
        float a0 = ab[0], a1 = ab[1];
#pragma unroll
        for (int l = 0; l < NLAT; ++l) { a0 += lat[l]*aW[l]; a1 += lat[l]*aW[NLAT+l]; }
        float m = fmaxf(a0, a1);
        float e0 = __expf(a0 - m), e1 = __expf(a1 - m);
        float inv = frcp(e0 + e1);
        float2 av; av.x = e0*inv; av.y = e1*inv;
        *reinterpret_cast<float2*>(pA + hh*2) = av;
        // proto: sigmoid, 5x float2
#pragma unroll
        for (int p = 0; p < PDIM/2; ++p) {
            float s0 = pb[2*p],   s1 = pb[2*p+1];
#pragma unroll
            for (int l = 0; l < NLAT; ++l) {
                s0 += lat[l] * pW[(2*p)*NLAT + l];
                s1 += lat[l] * pW[(2*p+1)*NLAT + l];
            }
            float2 pv; pv.x = fsig(s0); pv.y = fsig(s1);
            *reinterpret_cast<float2*>(pP + hh*10 + 2*p) = pv;
        }
    }
}

extern "C" void kernel_launch(void* const* d_in, const int* in_sizes, int n_in,
                              void* d_out, int out_size, void* d_ws, size_t ws_size,
                              hipStream_t stream) {
    const float* t    = (const float*)d_in[0];
    const float* h0   = (const float*)d_in[2];
    const float* Wih  = (const float*)d_in[3];
    const float* Whh  = (const float*)d_in[4];
    const float* bih  = (const float*)d_in[5];
    const float* bhh  = (const float*)d_in[6];
    const float* gatW = (const float*)d_in[7];
    const float* gal  = (const float*)d_in[8];
    const float* gar  = (const float*)d_in[9];
    const float* Win  = (const float*)d_in[10];
    const float* bin  = (const float*)d_in[11];
    const float* Wout = (const float*)d_in[12];
    const float* bout = (const float*)d_in[13];
    const float* encW = (const float*)d_in[14];
    const float* encb = (const float*)d_in[15];
    const float* aW   = (const float*)d_in[16];
    const float* ab   = (const float*)d_in[17];
    const float* pW   = (const float*)d_in[18];
    const float* pb   = (const float*)d_in[19];

    const int B = in_sizes[0] / (NW * NF);
    float* outA = (float*)d_out;
    float* outP = (float*)d_out + (size_t)B * 32;

    k_fused<<<dim3((B + 255) / 256), dim3(256), 0, stream>>>(
        t, h0, Wih, Whh, bih, bhh, gatW, gal, gar, Win, bin, Wout, bout,
        encW, encb, aW, ab, pW, pb, outA, outP, B);
}

// Round 3
// 123.398 us; speedup vs baseline: 2.0696x; 1.5513x over previous
//
#include <hip/hip_runtime.h>

#define NW 3
#define NF 48
#define NHOST 16
#define NLAT 10
#define GOUT 16
#define EDIM 19
#define PDIM 10

// const-buffer layout (floats)
#define CB_M   0      // 19x19  Wq^T Wk
#define CB_P   361    // 19x19  Wout Wv
#define CB_G   722    // 19     bq^T Wk
#define CB_H   741    // 19     Wq^T bk
#define CB_R   760    // 19     Wout bv + bout
#define CB_C0  779    // 1      bq.bk
#define CB_WAL 780    // 3      gatW @ gal
#define CB_WAR 783    // 3      gatW @ gar
#define CB_N   786

__device__ __forceinline__ float frcp(float x){ return __builtin_amdgcn_rcpf(x); }
__device__ __forceinline__ float fsig(float x){ return frcp(1.f + __expf(-x)); }
__device__ __forceinline__ float ftanh(float x){ return 1.f - 2.f*frcp(1.f + __expf(2.f*x)); }

// ---------------- K0: fold MHA weights (tiny) ----------------
__global__ void k_const(const float* __restrict__ Win, const float* __restrict__ bin,
                        const float* __restrict__ Wout, const float* __restrict__ bout,
                        const float* __restrict__ gatW, const float* __restrict__ gal,
                        const float* __restrict__ gar, float* __restrict__ cb)
{
    for (int idx = threadIdx.x; idx < CB_N; idx += blockDim.x) {
        float acc = 0.f;
        if (idx < 361) {                       // M[i][j] = sum_e Wq[e][i] Wk[e][j]
            int i = idx/19, j = idx%19;
            for (int e = 0; e < EDIM; ++e) acc += Win[e*EDIM+i]*Win[(EDIM+e)*EDIM+j];
        } else if (idx < 722) {                // P[i][j] = sum_e Wout[i][e] Wv[e][j]
            int k = idx-361; int i = k/19, j = k%19;
            for (int e = 0; e < EDIM; ++e) acc += Wout[i*EDIM+e]*Win[(2*EDIM+e)*EDIM+j];
        } else if (idx < 741) {                // g[j] = sum_e bq[e] Wk[e][j]
            int j = idx-722;
            for (int e = 0; e < EDIM; ++e) acc += bin[e]*Win[(EDIM+e)*EDIM+j];
        } else if (idx < 760) {                // h[i] = sum_e Wq[e][i] bk[e]
            int i = idx-741;
            for (int e = 0; e < EDIM; ++e) acc += Win[e*EDIM+i]*bin[EDIM+e];
        } else if (idx < 779) {                // r[i] = Wout bv + bout
            int i = idx-760; acc = bout[i];
            for (int e = 0; e < EDIM; ++e) acc += Wout[i*EDIM+e]*bin[2*EDIM+e];
        } else if (idx == 779) {               // c0 = bq.bk
            for (int e = 0; e < EDIM; ++e) acc += bin[e]*bin[EDIM+e];
        } else {                               // Wal/War
            int c = idx-780; int cc = c%3; bool left = c<3;
            for (int f2 = 0; f2 < GOUT; ++f2)
                acc += gatW[cc*GOUT+f2]*(left ? gal[f2] : gar[f2]);
        }
        cb[idx] = acc;
    }
}

// ---------------- K1: per-(b,w) GRU-gi + GAT -> ws1[25 streams][B] ----------------
__global__ __launch_bounds__(256) void k_front(
    const float* __restrict__ t, const float* __restrict__ Wih, const float* __restrict__ bih,
    const float* __restrict__ gatW, const float* __restrict__ cb,
    float* __restrict__ ws1, int B)
{
    const int b = blockIdx.x*blockDim.x + threadIdx.x;
    const int w = blockIdx.y;
    if (b >= B) return;

    float x[NF];
    const float* tp = t + ((size_t)b*NW + w)*NF;
#pragma unroll
    for (int i = 0; i < NF/4; ++i) {
        float4 v = *reinterpret_cast<const float4*>(tp + i*4);
        x[i*4+0]=v.x; x[i*4+1]=v.y; x[i*4+2]=v.z; x[i*4+3]=v.w;
    }
    float* o = ws1 + (size_t)w*25*B + b;       // stream k lives at o[k*B]
    // gi = Wih x + bih
#pragma unroll
    for (int r = 0; r < 9; ++r) {
        float acc = bih[r];
#pragma unroll
        for (int j = 0; j < NF; ++j) acc += x[j]*Wih[r*NF+j];
        o[(size_t)r*B] = acc;
    }
    // GAT (collapsed)
    const float Wal0=cb[CB_WAL],Wal1=cb[CB_WAL+1],Wal2=cb[CB_WAL+2];
    const float War0=cb[CB_WAR],War1=cb[CB_WAR+1],War2=cb[CB_WAR+2];
    float el[NHOST], er[NHOST];
#pragma unroll
    for (int n = 0; n < NHOST; ++n) {
        el[n] = x[n*3+0]*Wal0 + x[n*3+1]*Wal1 + x[n*3+2]*Wal2;
        er[n] = x[n*3+0]*War0 + x[n*3+1]*War1 + x[n*3+2]*War2;
    }
    float beta[NHOST];
#pragma unroll
    for (int u = 0; u < NHOST; ++u) beta[u] = 0.f;
#pragma unroll
    for (int v = 0; v < NHOST; ++v) {
        float ee[NHOST]; float sum = 0.f;
#pragma unroll
        for (int u = 0; u < NHOST; ++u) {
            float s = er[v] + el[u];
            s = fmaxf(s, 0.2f*s);
            ee[u] = __expf(s); sum += ee[u];
        }
        float inv = frcp(sum);
#pragma unroll
        for (int u = 0; u < NHOST; ++u) beta[u] += ee[u]*inv;
    }
    float g0=0.f, g1=0.f, g2=0.f;
#pragma unroll
    for (int u = 0; u < NHOST; ++u) {
        float bu = beta[u]*(1.f/16.f);
        g0 += bu*x[u*3+0]; g1 += bu*x[u*3+1]; g2 += bu*x[u*3+2];
    }
#pragma unroll
    for (int f2 = 0; f2 < GOUT; ++f2)
        o[(size_t)(9+f2)*B] = g0*gatW[f2] + g1*gatW[GOUT+f2] + g2*gatW[2*GOUT+f2];
}

// ---------------- K2: per-b GRU chain + folded MHA -> ws2[57][B] ----------------
__global__ __attribute__((amdgpu_flat_work_group_size(256,256), amdgpu_waves_per_eu(1,1)))
void k_mid(const float* __restrict__ ws1, const float* __restrict__ h0,
           const float* __restrict__ Whh, const float* __restrict__ bhh,
           const float* __restrict__ cb, float* __restrict__ ws2, int B)
{
    const int b = blockIdx.x*blockDim.x + threadIdx.x;
    if (b >= B) return;

    float h[3] = { h0[b*3+0], h0[b*3+1], h0[b*3+2] };
    float cw[NW][EDIM];
#pragma unroll
    for (int w = 0; w < NW; ++w) {
        const float* i1 = ws1 + (size_t)w*25*B + b;
        float gi[9];
#pragma unroll
        for (int r = 0; r < 9; ++r) gi[r] = i1[(size_t)r*B];
        float gh[9];
#pragma unroll
        for (int r = 0; r < 9; ++r)
            gh[r] = bhh[r] + h[0]*Whh[r*3+0] + h[1]*Whh[r*3+1] + h[2]*Whh[r*3+2];
#pragma unroll
        for (int j = 0; j < 3; ++j) {
            float rg = fsig(gi[j]   + gh[j]);
            float zg = fsig(gi[3+j] + gh[3+j]);
            float ng = ftanh(gi[6+j] + rg*gh[6+j]);
            h[j] = (1.f - zg)*ng + zg*h[j];
        }
        cw[w][0]=h[0]; cw[w][1]=h[1]; cw[w][2]=h[2];
#pragma unroll
        for (int f2 = 0; f2 < GOUT; ++f2) cw[w][3+f2] = i1[(size_t)(9+f2)*B];
    }
    // scores_st = (cs.M.ct + g.ct + h.cs + c0)/sqrt(E)
    float hs[NW];
#pragma unroll
    for (int s = 0; s < NW; ++s) {
        float a = 0.f;
#pragma unroll
        for (int i = 0; i < EDIM; ++i) a += cw[s][i]*cb[CB_H+i];
        hs[s] = a;
    }
    const float c0 = cb[CB_C0];
    float sc[NW][NW];
#pragma unroll
    for (int tt = 0; tt < NW; ++tt) {
        float mt[EDIM];
#pragma unroll
        for (int i = 0; i < EDIM; ++i) {
            float a = 0.f;
#pragma unroll
            for (int j = 0; j < EDIM; ++j) a += cb[CB_M+i*EDIM+j]*cw[tt][j];
            mt[i] = a;
        }
        float gt = 0.f;
#pragma unroll
        for (int j = 0; j < EDIM; ++j) gt += cb[CB_G+j]*cw[tt][j];
#pragma unroll
        for (int s = 0; s < NW; ++s) {
            float a = 0.f;
#pragma unroll
            for (int i = 0; i < EDIM; ++i) a += cw[s][i]*mt[i];
            sc[s][tt] = (a + gt + hs[s] + c0) * 0.2294157338705618f;
        }
    }
    float attw[NW][NW];
#pragma unroll
    for (int s = 0; s < NW; ++s) {
        float m = fmaxf(sc[s][0], fmaxf(sc[s][1], sc[s][2]));
        float e0=__expf(sc[s][0]-m), e1=__expf(sc[s][1]-m), e2=__expf(sc[s][2]-m);
        float inv = frcp(e0+e1+e2);
        attw[s][0]=e0*inv; attw[s][1]=e1*inv; attw[s][2]=e2*inv;
    }
    // f_s = sum_t attw_st * (P ct) + r
    float fac[NW][EDIM];
#pragma unroll
    for (int s = 0; s < NW; ++s)
#pragma unroll
        for (int i = 0; i < EDIM; ++i) fac[s][i] = cb[CB_R+i];
#pragma unroll
    for (int tt = 0; tt < NW; ++tt) {
        float pc[EDIM];
#pragma unroll
        for (int i = 0; i < EDIM; ++i) {
            float a = 0.f;
#pragma unroll
            for (int j = 0; j < EDIM; ++j) a += cb[CB_P+i*EDIM+j]*cw[tt][j];
            pc[i] = a;
        }
#pragma unroll
        for (int s = 0; s < NW; ++s)
#pragma unroll
            for (int i = 0; i < EDIM; ++i) fac[s][i] += attw[s][tt]*pc[i];
    }
#pragma unroll
    for (int s = 0; s < NW; ++s)
#pragma unroll
        for (int i = 0; i < EDIM; ++i)
            ws2[(size_t)(s*EDIM+i)*B + b] = fac[s][i];
}

// ---------------- K3: per-(b,host) encoder + heads, encW in LDS ----------------
__global__ __launch_bounds__(512) void k_enc(
    const float* __restrict__ ws2, const float* __restrict__ encW, const float* __restrict__ encb,
    const float* __restrict__ aW, const float* __restrict__ ab,
    const float* __restrict__ pW, const float* __restrict__ pb,
    float* __restrict__ outA, float* __restrict__ outP, int B)
{
    // enc row (hh*10+l) stored at LDS row (l*16+hh), stride 60 (16B-aligned, odd/32 banks)
    __shared__ float W[160*60];
    __shared__ float eb[160];
    for (int i = threadIdx.x; i < 160*57; i += blockDim.x) {
        int row = i/57, col = i - row*57;
        W[((row%10)*16 + row/10)*60 + col] = encW[i];
    }
    for (int i = threadIdx.x; i < 160; i += blockDim.x) eb[i] = encb[i];
    __syncthreads();

    const int tid = blockIdx.x*blockDim.x + threadIdx.x;
    const int b = tid >> 4, hh = tid & 15;
    if (b >= B) return;

    float f[57];
#pragma unroll
    for (int j = 0; j < 57; ++j) f[j] = ws2[(size_t)j*B + b];

    float lat[NLAT];
#pragma unroll
    for (int l = 0; l < NLAT; ++l) {
        const float* wr = &W[(l*16 + hh)*60];
        float a = eb[hh*10 + l];
#pragma unroll
        for (int j = 0; j < 57; ++j) a += f[j]*wr[j];
        lat[l] = a;
    }
    float* pA = outA + (size_t)b*32 + hh*2;
    float* pP = outP + (size_t)b*160 + hh*10;
    // anomaly softmax
    float a0 = ab[0], a1 = ab[1];
#pragma unroll
    for (int l = 0; l < NLAT; ++l) { a0 += lat[l]*aW[l]; a1 += lat[l]*aW[NLAT+l]; }
    float m = fmaxf(a0, a1);
    float e0 = __expf(a0-m), e1 = __expf(a1-m);
    float inv = frcp(e0+e1);
    float2 av; av.x = e0*inv; av.y = e1*inv;
    *reinterpret_cast<float2*>(pA) = av;
    // proto sigmoid
#pragma unroll
    for (int p = 0; p < PDIM/2; ++p) {
        float s0 = pb[2*p], s1 = pb[2*p+1];
#pragma unroll
        for (int l = 0; l < NLAT; ++l) {
            s0 += lat[l]*pW[(2*p)*NLAT+l];
            s1 += lat[l]*pW[(2*p+1)*NLAT+l];
        }
        float2 pv; pv.x = fsig(s0); pv.y = fsig(s1);
        *reinterpret_cast<float2*>(pP + 2*p) = pv;
    }
}

extern "C" void kernel_launch(void* const* d_in, const int* in_sizes, int n_in,
                              void* d_out, int out_size, void* d_ws, size_t ws_size,
                              hipStream_t stream) {
    const float* t    = (const float*)d_in[0];
    const float* h0   = (const float*)d_in[2];
    const float* Wih  = (const float*)d_in[3];
    const float* Whh  = (const float*)d_in[4];
    const float* bih  = (const float*)d_in[5];
    const float* bhh  = (const float*)d_in[6];
    const float* gatW = (const float*)d_in[7];
    const float* gal  = (const float*)d_in[8];
    const float* gar  = (const float*)d_in[9];
    const float* Win  = (const float*)d_in[10];
    const float* bin  = (const float*)d_in[11];
    const float* Wout = (const float*)d_in[12];
    const float* bout = (const float*)d_in[13];
    const float* encW = (const float*)d_in[14];
    const float* encb = (const float*)d_in[15];
    const float* aW   = (const float*)d_in[16];
    const float* ab   = (const float*)d_in[17];
    const float* pW   = (const float*)d_in[18];
    const float* pb   = (const float*)d_in[19];

    const int B = in_sizes[0] / (NW * NF);
    float* cb  = (float*)d_ws;
    float* ws1 = cb + 1024;
    float* ws2 = ws1 + (size_t)25*NW*B;
    float* outA = (float*)d_out;
    float* outP = (float*)d_out + (size_t)B*32;

    k_const<<<1, 512, 0, stream>>>(Win, bin, Wout, bout, gatW, gal, gar, cb);
    k_front<<<dim3((B+255)/256, NW), 256, 0, stream>>>(t, Wih, bih, gatW, cb, ws1, B);
    k_mid<<<dim3((B+255)/256), 256, 0, stream>>>(ws1, h0, Whh, bhh, cb, ws2, B);
    k_enc<<<dim3((B*16+511)/512), 512, 0, stream>>>(ws2, encW, encb, aW, ab, pW, pb, outA, outP, B);
}

// Round 4
// 118.197 us; speedup vs baseline: 2.1606x; 1.0440x over previous
//
#include <hip/hip_runtime.h>

#define NW 3
#define NF 48
#define NHOST 16
#define NLAT 10
#define GOUT 16
#define EDIM 19
#define PDIM 10

// const-buffer layout (floats)
#define CB_M   0      // 19x19  Wq^T Wk
#define CB_P   361    // 19x19  Wout Wv
#define CB_G   722    // 19     bq^T Wk
#define CB_H   741    // 19     Wq^T bk
#define CB_R   760    // 19     Wout bv + bout
#define CB_C0  779    // 1      bq.bk
#define CB_WAL 780    // 3      gatW @ gal
#define CB_WAR 783    // 3      gatW @ gar
#define CB_N   786

__device__ __forceinline__ float frcp(float x){ return __builtin_amdgcn_rcpf(x); }
__device__ __forceinline__ float fsig(float x){ return frcp(1.f + __expf(-x)); }
__device__ __forceinline__ float ftanh(float x){ return 1.f - 2.f*frcp(1.f + __expf(2.f*x)); }

// ---------------- K0: fold MHA weights (tiny) ----------------
__global__ void k_const(const float* __restrict__ Win, const float* __restrict__ bin,
                        const float* __restrict__ Wout, const float* __restrict__ bout,
                        const float* __restrict__ gatW, const float* __restrict__ gal,
                        const float* __restrict__ gar, float* __restrict__ cb)
{
    for (int idx = threadIdx.x; idx < CB_N; idx += blockDim.x) {
        float acc = 0.f;
        if (idx < 361) {                       // M[i][j] = sum_e Wq[e][i] Wk[e][j]
            int i = idx/19, j = idx%19;
            for (int e = 0; e < EDIM; ++e) acc += Win[e*EDIM+i]*Win[(EDIM+e)*EDIM+j];
        } else if (idx < 722) {                // P[i][j] = sum_e Wout[i][e] Wv[e][j]
            int k = idx-361; int i = k/19, j = k%19;
            for (int e = 0; e < EDIM; ++e) acc += Wout[i*EDIM+e]*Win[(2*EDIM+e)*EDIM+j];
        } else if (idx < 741) {                // g[j] = sum_e bq[e] Wk[e][j]
            int j = idx-722;
            for (int e = 0; e < EDIM; ++e) acc += bin[e]*Win[(EDIM+e)*EDIM+j];
        } else if (idx < 760) {                // h[i] = sum_e Wq[e][i] bk[e]
            int i = idx-741;
            for (int e = 0; e < EDIM; ++e) acc += Win[e*EDIM+i]*bin[EDIM+e];
        } else if (idx < 779) {                // r[i] = Wout bv + bout
            int i = idx-760; acc = bout[i];
            for (int e = 0; e < EDIM; ++e) acc += Wout[i*EDIM+e]*bin[2*EDIM+e];
        } else if (idx == 779) {               // c0 = bq.bk
            for (int e = 0; e < EDIM; ++e) acc += bin[e]*bin[EDIM+e];
        } else {                               // Wal/War
            int c = idx-780; int cc = c%3; bool left = c<3;
            for (int f2 = 0; f2 < GOUT; ++f2)
                acc += gatW[cc*GOUT+f2]*(left ? gal[f2] : gar[f2]);
        }
        cb[idx] = acc;
    }
}

// ---------------- K1: per-(b,w) GRU-gi + GAT -> ws1[25 streams][B] ----------------
__global__ __launch_bounds__(256) void k_front(
    const float* __restrict__ t, const float* __restrict__ Wih, const float* __restrict__ bih,
    const float* __restrict__ gatW, const float* __restrict__ cb,
    float* __restrict__ ws1, int B)
{
    const int b = blockIdx.x*blockDim.x + threadIdx.x;
    const int w = blockIdx.y;
    if (b >= B) return;

    float x[NF];
    const float* tp = t + ((size_t)b*NW + w)*NF;
#pragma unroll
    for (int i = 0; i < NF/4; ++i) {
        float4 v = *reinterpret_cast<const float4*>(tp + i*4);
        x[i*4+0]=v.x; x[i*4+1]=v.y; x[i*4+2]=v.z; x[i*4+3]=v.w;
    }
    float* o = ws1 + (size_t)w*25*B + b;       // stream k lives at o[k*B]
    // gi = Wih x + bih
#pragma unroll
    for (int r = 0; r < 9; ++r) {
        float acc = bih[r];
#pragma unroll
        for (int j = 0; j < NF; ++j) acc += x[j]*Wih[r*NF+j];
        o[(size_t)r*B] = acc;
    }
    // GAT (collapsed)
    const float Wal0=cb[CB_WAL],Wal1=cb[CB_WAL+1],Wal2=cb[CB_WAL+2];
    const float War0=cb[CB_WAR],War1=cb[CB_WAR+1],War2=cb[CB_WAR+2];
    float el[NHOST], er[NHOST];
#pragma unroll
    for (int n = 0; n < NHOST; ++n) {
        el[n] = x[n*3+0]*Wal0 + x[n*3+1]*Wal1 + x[n*3+2]*Wal2;
        er[n] = x[n*3+0]*War0 + x[n*3+1]*War1 + x[n*3+2]*War2;
    }
    float beta[NHOST];
#pragma unroll
    for (int u = 0; u < NHOST; ++u) beta[u] = 0.f;
#pragma unroll
    for (int v = 0; v < NHOST; ++v) {
        float ee[NHOST]; float sum = 0.f;
#pragma unroll
        for (int u = 0; u < NHOST; ++u) {
            float s = er[v] + el[u];
            s = fmaxf(s, 0.2f*s);
            ee[u] = __expf(s); sum += ee[u];
        }
        float inv = frcp(sum);
#pragma unroll
        for (int u = 0; u < NHOST; ++u) beta[u] += ee[u]*inv;
    }
    float g0=0.f, g1=0.f, g2=0.f;
#pragma unroll
    for (int u = 0; u < NHOST; ++u) {
        float bu = beta[u]*(1.f/16.f);
        g0 += bu*x[u*3+0]; g1 += bu*x[u*3+1]; g2 += bu*x[u*3+2];
    }
#pragma unroll
    for (int f2 = 0; f2 < GOUT; ++f2)
        o[(size_t)(9+f2)*B] = g0*gatW[f2] + g1*gatW[GOUT+f2] + g2*gatW[2*GOUT+f2];
}

// ---------------- K2: per-b GRU chain + folded MHA -> ws2[57][B] ----------------
__global__ __attribute__((amdgpu_flat_work_group_size(256,256), amdgpu_waves_per_eu(1,1)))
void k_mid(const float* __restrict__ ws1, const float* __restrict__ h0,
           const float* __restrict__ Whh, const float* __restrict__ bhh,
           const float* __restrict__ cb, float* __restrict__ ws2, int B)
{
    const int b = blockIdx.x*blockDim.x + threadIdx.x;
    if (b >= B) return;

    float h[3] = { h0[b*3+0], h0[b*3+1], h0[b*3+2] };
    float cw[NW][EDIM];
#pragma unroll
    for (int w = 0; w < NW; ++w) {
        const float* i1 = ws1 + (size_t)w*25*B + b;
        float gi[9];
#pragma unroll
        for (int r = 0; r < 9; ++r) gi[r] = i1[(size_t)r*B];
        float gh[9];
#pragma unroll
        for (int r = 0; r < 9; ++r)
            gh[r] = bhh[r] + h[0]*Whh[r*3+0] + h[1]*Whh[r*3+1] + h[2]*Whh[r*3+2];
#pragma unroll
        for (int j = 0; j < 3; ++j) {
            float rg = fsig(gi[j]   + gh[j]);
            float zg = fsig(gi[3+j] + gh[3+j]);
            float ng = ftanh(gi[6+j] + rg*gh[6+j]);
            h[j] = (1.f - zg)*ng + zg*h[j];
        }
        cw[w][0]=h[0]; cw[w][1]=h[1]; cw[w][2]=h[2];
#pragma unroll
        for (int f2 = 0; f2 < GOUT; ++f2) cw[w][3+f2] = i1[(size_t)(9+f2)*B];
    }
    // scores_st = (cs.M.ct + g.ct + h.cs + c0)/sqrt(E)
    float hs[NW];
#pragma unroll
    for (int s = 0; s < NW; ++s) {
        float a = 0.f;
#pragma unroll
        for (int i = 0; i < EDIM; ++i) a += cw[s][i]*cb[CB_H+i];
        hs[s] = a;
    }
    const float c0 = cb[CB_C0];
    float sc[NW][NW];
#pragma unroll
    for (int tt = 0; tt < NW; ++tt) {
        float mt[EDIM];
#pragma unroll
        for (int i = 0; i < EDIM; ++i) {
            float a = 0.f;
#pragma unroll
            for (int j = 0; j < EDIM; ++j) a += cb[CB_M+i*EDIM+j]*cw[tt][j];
            mt[i] = a;
        }
        float gt = 0.f;
#pragma unroll
        for (int j = 0; j < EDIM; ++j) gt += cb[CB_G+j]*cw[tt][j];
#pragma unroll
        for (int s = 0; s < NW; ++s) {
            float a = 0.f;
#pragma unroll
            for (int i = 0; i < EDIM; ++i) a += cw[s][i]*mt[i];
            sc[s][tt] = (a + gt + hs[s] + c0) * 0.2294157338705618f;
        }
    }
    float attw[NW][NW];
#pragma unroll
    for (int s = 0; s < NW; ++s) {
        float m = fmaxf(sc[s][0], fmaxf(sc[s][1], sc[s][2]));
        float e0=__expf(sc[s][0]-m), e1=__expf(sc[s][1]-m), e2=__expf(sc[s][2]-m);
        float inv = frcp(e0+e1+e2);
        attw[s][0]=e0*inv; attw[s][1]=e1*inv; attw[s][2]=e2*inv;
    }
    // f_s = sum_t attw_st * (P ct) + r
    float fac[NW][EDIM];
#pragma unroll
    for (int s = 0; s < NW; ++s)
#pragma unroll
        for (int i = 0; i < EDIM; ++i) fac[s][i] = cb[CB_R+i];
#pragma unroll
    for (int tt = 0; tt < NW; ++tt) {
        float pc[EDIM];
#pragma unroll
        for (int i = 0; i < EDIM; ++i) {
            float a = 0.f;
#pragma unroll
            for (int j = 0; j < EDIM; ++j) a += cb[CB_P+i*EDIM+j]*cw[tt][j];
            pc[i] = a;
        }
#pragma unroll
        for (int s = 0; s < NW; ++s)
#pragma unroll
            for (int i = 0; i < EDIM; ++i) fac[s][i] += attw[s][tt]*pc[i];
    }
#pragma unroll
    for (int s = 0; s < NW; ++s)
#pragma unroll
        for (int i = 0; i < EDIM; ++i)
            ws2[(size_t)(s*EDIM+i)*B + b] = fac[s][i];
}

// ---------------- K3: per-(b, wave=host-quad) encoder + heads; encW via s_load ----------------
// b = blockIdx*64 + lane  (coalesced f loads); q = wave id, forced uniform via
// readfirstlane so encW row addresses are wave-uniform -> scalar K$ path.
__global__ __launch_bounds__(256) void k_enc(
    const float* __restrict__ ws2, const float* __restrict__ encW, const float* __restrict__ encb,
    const float* __restrict__ aW, const float* __restrict__ ab,
    const float* __restrict__ pW, const float* __restrict__ pb,
    float* __restrict__ outA, float* __restrict__ outP, int B)
{
    const int lane = threadIdx.x & 63;
    const int q = __builtin_amdgcn_readfirstlane(threadIdx.x >> 6); // 0..3, SGPR
    const int b = blockIdx.x*64 + lane;
    if (b >= B) return;

    float f[57];
#pragma unroll
    for (int j = 0; j < 57; ++j) f[j] = ws2[(size_t)j*B + b];

    const float dab = ab[0] - ab[1];
    float* pA = outA + (size_t)b*32;
    float* pP = outP + (size_t)b*160;

#pragma unroll
    for (int k = 0; k < 4; ++k) {
        const int hh = q*4 + k;               // wave-uniform
        float lat[NLAT];
#pragma unroll
        for (int l = 0; l < NLAT; ++l) {
            const int row = hh*NLAT + l;      // wave-uniform
            const float* wr = encW + row*57;
            float a = encb[row];
#pragma unroll
            for (int j = 0; j < 57; ++j) a += f[j]*wr[j];
            lat[l] = a;
        }
        // anomaly 2-class softmax == sigmoid of logit diff
        float d = dab;
#pragma unroll
        for (int l = 0; l < NLAT; ++l) d += lat[l]*(aW[l] - aW[NLAT+l]);
        float p0 = fsig(d);
        float2 av; av.x = p0; av.y = 1.f - p0;
        *reinterpret_cast<float2*>(pA + hh*2) = av;
        // proto sigmoid
#pragma unroll
        for (int p = 0; p < PDIM/2; ++p) {
            float s0 = pb[2*p], s1 = pb[2*p+1];
#pragma unroll
            for (int l = 0; l < NLAT; ++l) {
                s0 += lat[l]*pW[(2*p)*NLAT+l];
                s1 += lat[l]*pW[(2*p+1)*NLAT+l];
            }
            float2 pv; pv.x = fsig(s0); pv.y = fsig(s1);
            *reinterpret_cast<float2*>(pP + hh*10 + 2*p) = pv;
        }
    }
}

extern "C" void kernel_launch(void* const* d_in, const int* in_sizes, int n_in,
                              void* d_out, int out_size, void* d_ws, size_t ws_size,
                              hipStream_t stream) {
    const float* t    = (const float*)d_in[0];
    const float* h0   = (const float*)d_in[2];
    const float* Wih  = (const float*)d_in[3];
    const float* Whh  = (const float*)d_in[4];
    const float* bih  = (const float*)d_in[5];
    const float* bhh  = (const float*)d_in[6];
    const float* gatW = (const float*)d_in[7];
    const float* gal  = (const float*)d_in[8];
    const float* gar  = (const float*)d_in[9];
    const float* Win  = (const float*)d_in[10];
    const float* bin  = (const float*)d_in[11];
    const float* Wout = (const float*)d_in[12];
    const float* bout = (const float*)d_in[13];
    const float* encW = (const float*)d_in[14];
    const float* encb = (const float*)d_in[15];
    const float* aW   = (const float*)d_in[16];
    const float* ab   = (const float*)d_in[17];
    const float* pW   = (const float*)d_in[18];
    const float* pb   = (const float*)d_in[19];

    const int B = in_sizes[0] / (NW * NF);
    float* cb  = (float*)d_ws;
    float* ws1 = cb + 1024;
    float* ws2 = ws1 + (size_t)25*NW*B;
    float* outA = (float*)d_out;
    float* outP = (float*)d_out + (size_t)B*32;

    k_const<<<1, 512, 0, stream>>>(Win, bin, Wout, bout, gatW, gal, gar, cb);
    k_front<<<dim3((B+255)/256, NW), 256, 0, stream>>>(t, Wih, bih, gatW, cb, ws1, B);
    k_mid<<<dim3((B+255)/256), 256, 0, stream>>>(ws1, h0, Whh, bhh, cb, ws2, B);
    k_enc<<<dim3((B+63)/64), 256, 0, stream>>>(ws2, encW, encb, aW, ab, pW, pb, outA, outP, B);
}

// Round 5
// 114.781 us; speedup vs baseline: 2.2249x; 1.0298x over previous
//
#include <hip/hip_runtime.h>

#define NW 3
#define NF 48
#define NHOST 16
#define NLAT 10
#define GOUT 16
#define EDIM 19
#define PDIM 10

// const-buffer layout (floats)
#define CB_M   0      // 19x19  Wq^T Wk
#define CB_P   361    // 19x19  Wout Wv
#define CB_G   722    // 19     bq^T Wk
#define CB_H   741    // 19     Wq^T bk
#define CB_R   760    // 19     Wout bv + bout
#define CB_C0  779    // 1      bq.bk
#define CB_WAL 780    // 3      gatW @ gal
#define CB_WAR 783    // 3      gatW @ gar
#define CB_N   786

__device__ __forceinline__ float frcp(float x){ return __builtin_amdgcn_rcpf(x); }
__device__ __forceinline__ float fsig(float x){ return frcp(1.f + __expf(-x)); }
__device__ __forceinline__ float ftanh(float x){ return 1.f - 2.f*frcp(1.f + __expf(2.f*x)); }

// ---------------- K0: fold MHA weights (tiny) ----------------
__global__ void k_const(const float* __restrict__ Win, const float* __restrict__ bin,
                        const float* __restrict__ Wout, const float* __restrict__ bout,
                        const float* __restrict__ gatW, const float* __restrict__ gal,
                        const float* __restrict__ gar, float* __restrict__ cb)
{
    for (int idx = threadIdx.x; idx < CB_N; idx += blockDim.x) {
        float acc = 0.f;
        if (idx < 361) {                       // M[i][j] = sum_e Wq[e][i] Wk[e][j]
            int i = idx/19, j = idx%19;
            for (int e = 0; e < EDIM; ++e) acc += Win[e*EDIM+i]*Win[(EDIM+e)*EDIM+j];
        } else if (idx < 722) {                // P[i][j] = sum_e Wout[i][e] Wv[e][j]
            int k = idx-361; int i = k/19, j = k%19;
            for (int e = 0; e < EDIM; ++e) acc += Wout[i*EDIM+e]*Win[(2*EDIM+e)*EDIM+j];
        } else if (idx < 741) {                // g[j] = sum_e bq[e] Wk[e][j]
            int j = idx-722;
            for (int e = 0; e < EDIM; ++e) acc += bin[e]*Win[(EDIM+e)*EDIM+j];
        } else if (idx < 760) {                // h[i] = sum_e Wq[e][i] bk[e]
            int i = idx-741;
            for (int e = 0; e < EDIM; ++e) acc += Win[e*EDIM+i]*bin[EDIM+e];
        } else if (idx < 779) {                // r[i] = Wout bv + bout
            int i = idx-760; acc = bout[i];
            for (int e = 0; e < EDIM; ++e) acc += Wout[i*EDIM+e]*bin[2*EDIM+e];
        } else if (idx == 779) {               // c0 = bq.bk
            for (int e = 0; e < EDIM; ++e) acc += bin[e]*bin[EDIM+e];
        } else {                               // Wal/War
            int c = idx-780; int cc = c%3; bool left = c<3;
            for (int f2 = 0; f2 < GOUT; ++f2)
                acc += gatW[cc*GOUT+f2]*(left ? gal[f2] : gar[f2]);
        }
        cb[idx] = acc;
    }
}

// ---------------- K1: per-(b,w) GRU-gi + GAT -> ws1[25 streams][B] ----------------
__global__ __launch_bounds__(256) void k_front(
    const float* __restrict__ t, const float* __restrict__ Wih, const float* __restrict__ bih,
    const float* __restrict__ gatW, const float* __restrict__ cb,
    float* __restrict__ ws1, int B)
{
    const int b = blockIdx.x*blockDim.x + threadIdx.x;
    const int w = blockIdx.y;
    if (b >= B) return;

    float x[NF];
    const float* tp = t + ((size_t)b*NW + w)*NF;
#pragma unroll
    for (int i = 0; i < NF/4; ++i) {
        float4 v = *reinterpret_cast<const float4*>(tp + i*4);
        x[i*4+0]=v.x; x[i*4+1]=v.y; x[i*4+2]=v.z; x[i*4+3]=v.w;
    }
    float* o = ws1 + (size_t)w*25*B + b;       // stream k lives at o[k*B]
    // gi = Wih x + bih
#pragma unroll
    for (int r = 0; r < 9; ++r) {
        float acc = bih[r];
#pragma unroll
        for (int j = 0; j < NF; ++j) acc += x[j]*Wih[r*NF+j];
        o[(size_t)r*B] = acc;
    }
    // GAT (collapsed)
    const float Wal0=cb[CB_WAL],Wal1=cb[CB_WAL+1],Wal2=cb[CB_WAL+2];
    const float War0=cb[CB_WAR],War1=cb[CB_WAR+1],War2=cb[CB_WAR+2];
    float el[NHOST], er[NHOST];
#pragma unroll
    for (int n = 0; n < NHOST; ++n) {
        el[n] = x[n*3+0]*Wal0 + x[n*3+1]*Wal1 + x[n*3+2]*Wal2;
        er[n] = x[n*3+0]*War0 + x[n*3+1]*War1 + x[n*3+2]*War2;
    }
    float beta[NHOST];
#pragma unroll
    for (int u = 0; u < NHOST; ++u) beta[u] = 0.f;
#pragma unroll
    for (int v = 0; v < NHOST; ++v) {
        float ee[NHOST]; float sum = 0.f;
#pragma unroll
        for (int u = 0; u < NHOST; ++u) {
            float s = er[v] + el[u];
            s = fmaxf(s, 0.2f*s);
            ee[u] = __expf(s); sum += ee[u];
        }
        float inv = frcp(sum);
#pragma unroll
        for (int u = 0; u < NHOST; ++u) beta[u] += ee[u]*inv;
    }
    float g0=0.f, g1=0.f, g2=0.f;
#pragma unroll
    for (int u = 0; u < NHOST; ++u) {
        float bu = beta[u]*(1.f/16.f);
        g0 += bu*x[u*3+0]; g1 += bu*x[u*3+1]; g2 += bu*x[u*3+2];
    }
#pragma unroll
    for (int f2 = 0; f2 < GOUT; ++f2)
        o[(size_t)(9+f2)*B] = g0*gatW[f2] + g1*gatW[GOUT+f2] + g2*gatW[2*GOUT+f2];
}

// ---------------- K2: per-b GRU chain + folded MHA -> ws2[57][B] ----------------
__global__ __attribute__((amdgpu_flat_work_group_size(256,256), amdgpu_waves_per_eu(1,1)))
void k_mid(const float* __restrict__ ws1, const float* __restrict__ h0,
           const float* __restrict__ Whh, const float* __restrict__ bhh,
           const float* __restrict__ cb, float* __restrict__ ws2, int B)
{
    const int b = blockIdx.x*blockDim.x + threadIdx.x;
    if (b >= B) return;

    float h[3] = { h0[b*3+0], h0[b*3+1], h0[b*3+2] };
    float cw[NW][EDIM];
#pragma unroll
    for (int w = 0; w < NW; ++w) {
        const float* i1 = ws1 + (size_t)w*25*B + b;
        float gi[9];
#pragma unroll
        for (int r = 0; r < 9; ++r) gi[r] = i1[(size_t)r*B];
        float gh[9];
#pragma unroll
        for (int r = 0; r < 9; ++r)
            gh[r] = bhh[r] + h[0]*Whh[r*3+0] + h[1]*Whh[r*3+1] + h[2]*Whh[r*3+2];
#pragma unroll
        for (int j = 0; j < 3; ++j) {
            float rg = fsig(gi[j]   + gh[j]);
            float zg = fsig(gi[3+j] + gh[3+j]);
            float ng = ftanh(gi[6+j] + rg*gh[6+j]);
            h[j] = (1.f - zg)*ng + zg*h[j];
        }
        cw[w][0]=h[0]; cw[w][1]=h[1]; cw[w][2]=h[2];
#pragma unroll
        for (int f2 = 0; f2 < GOUT; ++f2) cw[w][3+f2] = i1[(size_t)(9+f2)*B];
    }
    // scores_st = (cs.M.ct + g.ct + h.cs + c0)/sqrt(E)
    float hs[NW];
#pragma unroll
    for (int s = 0; s < NW; ++s) {
        float a = 0.f;
#pragma unroll
        for (int i = 0; i < EDIM; ++i) a += cw[s][i]*cb[CB_H+i];
        hs[s] = a;
    }
    const float c0 = cb[CB_C0];
    float sc[NW][NW];
#pragma unroll
    for (int tt = 0; tt < NW; ++tt) {
        float mt[EDIM];
#pragma unroll
        for (int i = 0; i < EDIM; ++i) {
            float a = 0.f;
#pragma unroll
            for (int j = 0; j < EDIM; ++j) a += cb[CB_M+i*EDIM+j]*cw[tt][j];
            mt[i] = a;
        }
        float gt = 0.f;
#pragma unroll
        for (int j = 0; j < EDIM; ++j) gt += cb[CB_G+j]*cw[tt][j];
#pragma unroll
        for (int s = 0; s < NW; ++s) {
            float a = 0.f;
#pragma unroll
            for (int i = 0; i < EDIM; ++i) a += cw[s][i]*mt[i];
            sc[s][tt] = (a + gt + hs[s] + c0) * 0.2294157338705618f;
        }
    }
    float attw[NW][NW];
#pragma unroll
    for (int s = 0; s < NW; ++s) {
        float m = fmaxf(sc[s][0], fmaxf(sc[s][1], sc[s][2]));
        float e0=__expf(sc[s][0]-m), e1=__expf(sc[s][1]-m), e2=__expf(sc[s][2]-m);
        float inv = frcp(e0+e1+e2);
        attw[s][0]=e0*inv; attw[s][1]=e1*inv; attw[s][2]=e2*inv;
    }
    // f_s = sum_t attw_st * (P ct) + r
    float fac[NW][EDIM];
#pragma unroll
    for (int s = 0; s < NW; ++s)
#pragma unroll
        for (int i = 0; i < EDIM; ++i) fac[s][i] = cb[CB_R+i];
#pragma unroll
    for (int tt = 0; tt < NW; ++tt) {
        float pc[EDIM];
#pragma unroll
        for (int i = 0; i < EDIM; ++i) {
            float a = 0.f;
#pragma unroll
            for (int j = 0; j < EDIM; ++j) a += cb[CB_P+i*EDIM+j]*cw[tt][j];
            pc[i] = a;
        }
#pragma unroll
        for (int s = 0; s < NW; ++s)
#pragma unroll
            for (int i = 0; i < EDIM; ++i) fac[s][i] += attw[s][tt]*pc[i];
    }
#pragma unroll
    for (int s = 0; s < NW; ++s)
#pragma unroll
        for (int i = 0; i < EDIM; ++i)
            ws2[(size_t)(s*EDIM+i)*B + b] = fac[s][i];
}

// ---------------- K3: per-(b, wave=host-quad) encoder + heads; encW via s_load ----------------
// b = blockIdx*64 + lane  (coalesced f loads); q = wave id, forced uniform via
// readfirstlane so encW row addresses are wave-uniform -> scalar K$ path.
// waves_per_eu(2,4): VGPR cap 256 >> live set (~80); stops the RA from
// spilling/sinking f[] to chase high occupancy (R4: VGPR=44, 57MB scratch).
__global__ __attribute__((amdgpu_flat_work_group_size(256,256), amdgpu_waves_per_eu(2,4)))
void k_enc(
    const float* __restrict__ ws2, const float* __restrict__ encW, const float* __restrict__ encb,
    const float* __restrict__ aW, const float* __restrict__ ab,
    const float* __restrict__ pW, const float* __restrict__ pb,
    float* __restrict__ outA, float* __restrict__ outP, int B)
{
    const int lane = threadIdx.x & 63;
    const int q = __builtin_amdgcn_readfirstlane(threadIdx.x >> 6); // 0..3, SGPR
    const int b = blockIdx.x*64 + lane;
    if (b >= B) return;

    float f[57];
#pragma unroll
    for (int j = 0; j < 57; ++j) f[j] = ws2[(size_t)j*B + b];

    const float dab = ab[0] - ab[1];
    float* pA = outA + (size_t)b*32;
    float* pP = outP + (size_t)b*160;

#pragma unroll
    for (int k = 0; k < 4; ++k) {
        const int hh = q*4 + k;               // wave-uniform
        float lat[NLAT];
#pragma unroll
        for (int l = 0; l < NLAT; ++l) {
            const int row = hh*NLAT + l;      // wave-uniform
            const float* wr = encW + row*57;
            float a = encb[row];
#pragma unroll
            for (int j = 0; j < 57; ++j) a += f[j]*wr[j];
            lat[l] = a;
        }
        // anomaly 2-class softmax == sigmoid of logit diff
        float d = dab;
#pragma unroll
        for (int l = 0; l < NLAT; ++l) d += lat[l]*(aW[l] - aW[NLAT+l]);
        float p0 = fsig(d);
        float2 av; av.x = p0; av.y = 1.f - p0;
        *reinterpret_cast<float2*>(pA + hh*2) = av;
        // proto sigmoid
#pragma unroll
        for (int p = 0; p < PDIM/2; ++p) {
            float s0 = pb[2*p], s1 = pb[2*p+1];
#pragma unroll
            for (int l = 0; l < NLAT; ++l) {
                s0 += lat[l]*pW[(2*p)*NLAT+l];
                s1 += lat[l]*pW[(2*p+1)*NLAT+l];
            }
            float2 pv; pv.x = fsig(s0); pv.y = fsig(s1);
            *reinterpret_cast<float2*>(pP + hh*10 + 2*p) = pv;
        }
    }
}

extern "C" void kernel_launch(void* const* d_in, const int* in_sizes, int n_in,
                              void* d_out, int out_size, void* d_ws, size_t ws_size,
                              hipStream_t stream) {
    const float* t    = (const float*)d_in[0];
    const float* h0   = (const float*)d_in[2];
    const float* Wih  = (const float*)d_in[3];
    const float* Whh  = (const float*)d_in[4];
    const float* bih  = (const float*)d_in[5];
    const float* bhh  = (const float*)d_in[6];
    const float* gatW = (const float*)d_in[7];
    const float* gal  = (const float*)d_in[8];
    const float* gar  = (const float*)d_in[9];
    const float* Win  = (const float*)d_in[10];
    const float* bin  = (const float*)d_in[11];
    const float* Wout = (const float*)d_in[12];
    const float* bout = (const float*)d_in[13];
    const float* encW = (const float*)d_in[14];
    const float* encb = (const float*)d_in[15];
    const float* aW   = (const float*)d_in[16];
    const float* ab   = (const float*)d_in[17];
    const float* pW   = (const float*)d_in[18];
    const float* pb   = (const float*)d_in[19];

    const int B = in_sizes[0] / (NW * NF);
    float* cb  = (float*)d_ws;
    float* ws1 = cb + 1024;
    float* ws2 = ws1 + (size_t)25*NW*B;
    float* outA = (float*)d_out;
    float* outP = (float*)d_out + (size_t)B*32;

    k_const<<<1, 512, 0, stream>>>(Win, bin, Wout, bout, gatW, gal, gar, cb);
    k_front<<<dim3((B+255)/256, NW), 256, 0, stream>>>(t, Wih, bih, gatW, cb, ws1, B);
    k_mid<<<dim3((B+255)/256), 256, 0, stream>>>(ws1, h0, Whh, bhh, cb, ws2, B);
    k_enc<<<dim3((B+63)/64), 256, 0, stream>>>(ws2, encW, encb, aW, ab, pW, pb, outA, outP, B);
}

// Round 6
// 113.292 us; speedup vs baseline: 2.2542x; 1.0131x over previous
//
#include <hip/hip_runtime.h>

#define NW 3
#define NF 48
#define NHOST 16
#define NLAT 10
#define GOUT 16
#define EDIM 19
#define PDIM 10

// const-buffer layout (floats)
#define CB_M   0      // 19x19  Wq^T Wk
#define CB_P   361    // 19x19  Wout Wv
#define CB_G   722    // 19     bq^T Wk
#define CB_H   741    // 19     Wq^T bk
#define CB_R   760    // 19     Wout bv + bout
#define CB_C0  779    // 1      bq.bk
#define CB_WAL 780    // 3      gatW @ gal
#define CB_WAR 783    // 3      gatW @ gar
#define CB_N   786
#define CB_ENCW 800   // 9216   encW copy, zero-padded to 9216
#define CB_TOT  10240

__device__ __forceinline__ float frcp(float x){ return __builtin_amdgcn_rcpf(x); }
__device__ __forceinline__ float fsig(float x){ return frcp(1.f + __expf(-x)); }
__device__ __forceinline__ float ftanh(float x){ return 1.f - 2.f*frcp(1.f + __expf(2.f*x)); }

// ---------------- K0: fold MHA weights + padded encW copy ----------------
__global__ void k_const(const float* __restrict__ Win, const float* __restrict__ bin,
                        const float* __restrict__ Wout, const float* __restrict__ bout,
                        const float* __restrict__ gatW, const float* __restrict__ gal,
                        const float* __restrict__ gar, const float* __restrict__ encW,
                        float* __restrict__ cb)
{
    for (int idx = threadIdx.x; idx < CB_N; idx += blockDim.x) {
        float acc = 0.f;
        if (idx < 361) {                       // M[i][j] = sum_e Wq[e][i] Wk[e][j]
            int i = idx/19, j = idx%19;
            for (int e = 0; e < EDIM; ++e) acc += Win[e*EDIM+i]*Win[(EDIM+e)*EDIM+j];
        } else if (idx < 722) {                // P[i][j] = sum_e Wout[i][e] Wv[e][j]
            int k = idx-361; int i = k/19, j = k%19;
            for (int e = 0; e < EDIM; ++e) acc += Wout[i*EDIM+e]*Win[(2*EDIM+e)*EDIM+j];
        } else if (idx < 741) {                // g[j] = sum_e bq[e] Wk[e][j]
            int j = idx-722;
            for (int e = 0; e < EDIM; ++e) acc += bin[e]*Win[(EDIM+e)*EDIM+j];
        } else if (idx < 760) {                // h[i] = sum_e Wq[e][i] bk[e]
            int i = idx-741;
            for (int e = 0; e < EDIM; ++e) acc += Win[e*EDIM+i]*bin[EDIM+e];
        } else if (idx < 779) {                // r[i] = Wout bv + bout
            int i = idx-760; acc = bout[i];
            for (int e = 0; e < EDIM; ++e) acc += Wout[i*EDIM+e]*bin[2*EDIM+e];
        } else if (idx == 779) {               // c0 = bq.bk
            for (int e = 0; e < EDIM; ++e) acc += bin[e]*bin[EDIM+e];
        } else {                               // Wal/War
            int c = idx-780; int cc = c%3; bool left = c<3;
            for (int f2 = 0; f2 < GOUT; ++f2)
                acc += gatW[cc*GOUT+f2]*(left ? gal[f2] : gar[f2]);
        }
        cb[idx] = acc;
    }
    // padded encW copy (element 9120.. = 0) so the K-split's 29th FMA is a no-op
    for (int idx = threadIdx.x; idx < 9216; idx += blockDim.x)
        cb[CB_ENCW + idx] = (idx < 160*57) ? encW[idx] : 0.f;
}

// ---------------- K1: per-(b,w) GRU-gi + GAT -> ws1[25 streams][B] ----------------
__global__ __launch_bounds__(256) void k_front(
    const float* __restrict__ t, const float* __restrict__ Wih, const float* __restrict__ bih,
    const float* __restrict__ gatW, const float* __restrict__ cb,
    float* __restrict__ ws1, int B)
{
    const int b = blockIdx.x*blockDim.x + threadIdx.x;
    const int w = blockIdx.y;
    if (b >= B) return;

    float x[NF];
    const float* tp = t + ((size_t)b*NW + w)*NF;
#pragma unroll
    for (int i = 0; i < NF/4; ++i) {
        float4 v = *reinterpret_cast<const float4*>(tp + i*4);
        x[i*4+0]=v.x; x[i*4+1]=v.y; x[i*4+2]=v.z; x[i*4+3]=v.w;
    }
    float* o = ws1 + (size_t)w*25*B + b;       // stream k lives at o[k*B]
    // gi = Wih x + bih
#pragma unroll
    for (int r = 0; r < 9; ++r) {
        float acc = bih[r];
#pragma unroll
        for (int j = 0; j < NF; ++j) acc += x[j]*Wih[r*NF+j];
        o[(size_t)r*B] = acc;
    }
    // GAT (collapsed)
    const float Wal0=cb[CB_WAL],Wal1=cb[CB_WAL+1],Wal2=cb[CB_WAL+2];
    const float War0=cb[CB_WAR],War1=cb[CB_WAR+1],War2=cb[CB_WAR+2];
    float el[NHOST], er[NHOST];
#pragma unroll
    for (int n = 0; n < NHOST; ++n) {
        el[n] = x[n*3+0]*Wal0 + x[n*3+1]*Wal1 + x[n*3+2]*Wal2;
        er[n] = x[n*3+0]*War0 + x[n*3+1]*War1 + x[n*3+2]*War2;
    }
    float beta[NHOST];
#pragma unroll
    for (int u = 0; u < NHOST; ++u) beta[u] = 0.f;
#pragma unroll
    for (int v = 0; v < NHOST; ++v) {
        float ee[NHOST]; float sum = 0.f;
#pragma unroll
        for (int u = 0; u < NHOST; ++u) {
            float s = er[v] + el[u];
            s = fmaxf(s, 0.2f*s);
            ee[u] = __expf(s); sum += ee[u];
        }
        float inv = frcp(sum);
#pragma unroll
        for (int u = 0; u < NHOST; ++u) beta[u] += ee[u]*inv;
    }
    float g0=0.f, g1=0.f, g2=0.f;
#pragma unroll
    for (int u = 0; u < NHOST; ++u) {
        float bu = beta[u]*(1.f/16.f);
        g0 += bu*x[u*3+0]; g1 += bu*x[u*3+1]; g2 += bu*x[u*3+2];
    }
#pragma unroll
    for (int f2 = 0; f2 < GOUT; ++f2)
        o[(size_t)(9+f2)*B] = g0*gatW[f2] + g1*gatW[GOUT+f2] + g2*gatW[2*GOUT+f2];
}

// ---------------- K2: per-b GRU chain + folded MHA -> ws2[57][B] ----------------
__global__ __attribute__((amdgpu_flat_work_group_size(256,256), amdgpu_waves_per_eu(1,1)))
void k_mid(const float* __restrict__ ws1, const float* __restrict__ h0,
           const float* __restrict__ Whh, const float* __restrict__ bhh,
           const float* __restrict__ cb, float* __restrict__ ws2, int B)
{
    const int b = blockIdx.x*blockDim.x + threadIdx.x;
    if (b >= B) return;

    float h[3] = { h0[b*3+0], h0[b*3+1], h0[b*3+2] };
    float cw[NW][EDIM];
#pragma unroll
    for (int w = 0; w < NW; ++w) {
        const float* i1 = ws1 + (size_t)w*25*B + b;
        float gi[9];
#pragma unroll
        for (int r = 0; r < 9; ++r) gi[r] = i1[(size_t)r*B];
        float gh[9];
#pragma unroll
        for (int r = 0; r < 9; ++r)
            gh[r] = bhh[r] + h[0]*Whh[r*3+0] + h[1]*Whh[r*3+1] + h[2]*Whh[r*3+2];
#pragma unroll
        for (int j = 0; j < 3; ++j) {
            float rg = fsig(gi[j]   + gh[j]);
            float zg = fsig(gi[3+j] + gh[3+j]);
            float ng = ftanh(gi[6+j] + rg*gh[6+j]);
            h[j] = (1.f - zg)*ng + zg*h[j];
        }
        cw[w][0]=h[0]; cw[w][1]=h[1]; cw[w][2]=h[2];
#pragma unroll
        for (int f2 = 0; f2 < GOUT; ++f2) cw[w][3+f2] = i1[(size_t)(9+f2)*B];
    }
    // scores_st = (cs.M.ct + g.ct + h.cs + c0)/sqrt(E)
    float hs[NW];
#pragma unroll
    for (int s = 0; s < NW; ++s) {
        float a = 0.f;
#pragma unroll
        for (int i = 0; i < EDIM; ++i) a += cw[s][i]*cb[CB_H+i];
        hs[s] = a;
    }
    const float c0 = cb[CB_C0];
    float sc[NW][NW];
#pragma unroll
    for (int tt = 0; tt < NW; ++tt) {
        float mt[EDIM];
#pragma unroll
        for (int i = 0; i < EDIM; ++i) {
            float a = 0.f;
#pragma unroll
            for (int j = 0; j < EDIM; ++j) a += cb[CB_M+i*EDIM+j]*cw[tt][j];
            mt[i] = a;
        }
        float gt = 0.f;
#pragma unroll
        for (int j = 0; j < EDIM; ++j) gt += cb[CB_G+j]*cw[tt][j];
#pragma unroll
        for (int s = 0; s < NW; ++s) {
            float a = 0.f;
#pragma unroll
            for (int i = 0; i < EDIM; ++i) a += cw[s][i]*mt[i];
            sc[s][tt] = (a + gt + hs[s] + c0) * 0.2294157338705618f;
        }
    }
    float attw[NW][NW];
#pragma unroll
    for (int s = 0; s < NW; ++s) {
        float m = fmaxf(sc[s][0], fmaxf(sc[s][1], sc[s][2]));
        float e0=__expf(sc[s][0]-m), e1=__expf(sc[s][1]-m), e2=__expf(sc[s][2]-m);
        float inv = frcp(e0+e1+e2);
        attw[s][0]=e0*inv; attw[s][1]=e1*inv; attw[s][2]=e2*inv;
    }
    // f_s = sum_t attw_st * (P ct) + r
    float fac[NW][EDIM];
#pragma unroll
    for (int s = 0; s < NW; ++s)
#pragma unroll
        for (int i = 0; i < EDIM; ++i) fac[s][i] = cb[CB_R+i];
#pragma unroll
    for (int tt = 0; tt < NW; ++tt) {
        float pc[EDIM];
#pragma unroll
        for (int i = 0; i < EDIM; ++i) {
            float a = 0.f;
#pragma unroll
            for (int j = 0; j < EDIM; ++j) a += cb[CB_P+i*EDIM+j]*cw[tt][j];
            pc[i] = a;
        }
#pragma unroll
        for (int s = 0; s < NW; ++s)
#pragma unroll
            for (int i = 0; i < EDIM; ++i) fac[s][i] += attw[s][tt]*pc[i];
    }
#pragma unroll
    for (int s = 0; s < NW; ++s)
#pragma unroll
        for (int i = 0; i < EDIM; ++i)
            ws2[(size_t)(s*EDIM+i)*B + b] = fac[s][i];
}

// ---------------- K3: encoder + heads, wave-level K-split ----------------
// Block = 64 b's x 4 waves. Wave = (half, host-group): half k-range is
// wave-uniform -> encW stays on scalar s_load path; per-thread live set is
// f[29]+lat[10] ~ 50 VGPRs -> no spill even at the RA's 64-VGPR budget.
// Partials meet in LDS (lane-contiguous, conflict-free), double-buffered,
// one barrier per host.
__global__ __launch_bounds__(256) void k_enc(
    const float* __restrict__ ws2, const float* __restrict__ cb, const float* __restrict__ encb,
    const float* __restrict__ aW, const float* __restrict__ ab,
    const float* __restrict__ pW, const float* __restrict__ pb,
    float* __restrict__ outA, float* __restrict__ outP, int B)
{
    __shared__ float part[2][2][2][NLAT][64];   // [buf][hgrp][half][l][lane]
    const int lane = threadIdx.x & 63;
    const int wv   = __builtin_amdgcn_readfirstlane(threadIdx.x >> 6);
    const int half = wv & 1;                    // k-half: 0 -> j 0..28, 1 -> j 29..56(+pad)
    const int hg   = wv >> 1;                   // host group: hosts hg*8 .. hg*8+7
    const int j0   = half * 29;
    const int b    = blockIdx.x*64 + lane;
    if (blockIdx.x*64 >= B) return;

    const float* encWp = cb + CB_ENCW;          // zero-padded to 9216

    float f[29];
#pragma unroll
    for (int j = 0; j < 29; ++j)
        f[j] = (j0 + j < 57) ? ws2[(size_t)(j0+j)*B + b] : 0.f;

    const float dab = ab[0] - ab[1];
    float* pA = outA + (size_t)b*32;
    float* pP = outP + (size_t)b*160;

    for (int hh = 0; hh < 8; ++hh) {
        const int host = hg*8 + hh;
        const int buf = hh & 1;
        // K-half partials for this host's 10 rows (weights: scalar path)
#pragma unroll
        for (int l = 0; l < NLAT; ++l) {
            const float* wr = encWp + (host*NLAT + l)*57 + j0;
            float a = 0.f;
#pragma unroll
            for (int j = 0; j < 29; ++j) a += f[j]*wr[j];
            part[buf][hg][half][l][lane] = a;
        }
        __syncthreads();
        float lat[NLAT];
#pragma unroll
        for (int l = 0; l < NLAT; ++l)
            lat[l] = part[buf][hg][0][l][lane] + part[buf][hg][1][l][lane]
                   + encb[host*NLAT + l];
        // heads (both halves compute; owner stores)
        float d = dab;
#pragma unroll
        for (int l = 0; l < NLAT; ++l) d += lat[l]*(aW[l] - aW[NLAT+l]);
        float p0 = fsig(d);
        float pr[PDIM];
#pragma unroll
        for (int p = 0; p < PDIM; ++p) {
            float s0 = pb[p];
#pragma unroll
            for (int l = 0; l < NLAT; ++l) s0 += lat[l]*pW[p*NLAT+l];
            pr[p] = fsig(s0);
        }
        if (half == (hh & 1)) {
            float2 av; av.x = p0; av.y = 1.f - p0;
            *reinterpret_cast<float2*>(pA + host*2) = av;
#pragma unroll
            for (int p = 0; p < PDIM/2; ++p) {
                float2 pv; pv.x = pr[2*p]; pv.y = pr[2*p+1];
                *reinterpret_cast<float2*>(pP + host*10 + 2*p) = pv;
            }
        }
    }
}

extern "C" void kernel_launch(void* const* d_in, const int* in_sizes, int n_in,
                              void* d_out, int out_size, void* d_ws, size_t ws_size,
                              hipStream_t stream) {
    const float* t    = (const float*)d_in[0];
    const float* h0   = (const float*)d_in[2];
    const float* Wih  = (const float*)d_in[3];
    const float* Whh  = (const float*)d_in[4];
    const float* bih  = (const float*)d_in[5];
    const float* bhh  = (const float*)d_in[6];
    const float* gatW = (const float*)d_in[7];
    const float* gal  = (const float*)d_in[8];
    const float* gar  = (const float*)d_in[9];
    const float* Win  = (const float*)d_in[10];
    const float* bin  = (const float*)d_in[11];
    const float* Wout = (const float*)d_in[12];
    const float* bout = (const float*)d_in[13];
    const float* encW = (const float*)d_in[14];
    const float* encb = (const float*)d_in[15];
    const float* aW   = (const float*)d_in[16];
    const float* ab   = (const float*)d_in[17];
    const float* pW   = (const float*)d_in[18];
    const float* pb   = (const float*)d_in[19];

    const int B = in_sizes[0] / (NW * NF);
    float* cb  = (float*)d_ws;
    float* ws1 = cb + CB_TOT;
    float* ws2 = ws1 + (size_t)25*NW*B;
    float* outA = (float*)d_out;
    float* outP = (float*)d_out + (size_t)B*32;

    k_const<<<1, 512, 0, stream>>>(Win, bin, Wout, bout, gatW, gal, gar, encW, cb);
    k_front<<<dim3((B+255)/256, NW), 256, 0, stream>>>(t, Wih, bih, gatW, cb, ws1, B);
    k_mid<<<dim3((B+255)/256), 256, 0, stream>>>(ws1, h0, Whh, bhh, cb, ws2, B);
    k_enc<<<dim3((B+63)/64), 256, 0, stream>>>(ws2, cb, encb, aW, ab, pW, pb, outA, outP, B);
}

// Round 8
// 110.380 us; speedup vs baseline: 2.3137x; 1.0264x over previous
//
#include <hip/hip_runtime.h>

#define NW 3
#define NF 48
#define NHOST 16
#define NLAT 10
#define GOUT 16
#define EDIM 19
#define PDIM 10

// const-buffer layout (floats)
#define CB_M    0     // 19x19  Wq^T Wk
#define CB_P    361   // 19x19  Wout Wv
#define CB_G    722   // 19     bq^T Wk
#define CB_H    741   // 19     Wq^T bk
#define CB_R    760   // 19     Wout bv + bout
#define CB_C0   779   // 1      bq.bk
#define CB_WAL  780   // 3      gatW @ gal
#define CB_WAR  783   // 3      gatW @ gar
#define CB_CBIG 800   // 176    folded head biases (g = host*11 + {diff,p0..p9})
#define CB_BF   976   // 11264 ushorts (5632 floats): B-frags of Wbig^T, bf16
#define CB_TOT  10240

typedef __attribute__((ext_vector_type(8))) short bf16x8;
typedef __attribute__((ext_vector_type(4))) float f32x4;

__device__ __forceinline__ float frcp(float x){ return __builtin_amdgcn_rcpf(x); }
__device__ __forceinline__ float fsig(float x){ return frcp(1.f + __expf(-x)); }
__device__ __forceinline__ float ftanh(float x){ return 1.f - 2.f*frcp(1.f + __expf(2.f*x)); }
__device__ __forceinline__ unsigned short f2bf(float x){
    union { float f; unsigned u; } v; v.f = x;
    unsigned r = v.u + 0x7FFFu + ((v.u >> 16) & 1u);
    return (unsigned short)(r >> 16);
}

// ---------------- K0: fold MHA weights + head-folded encoder B-frags ----------------
__global__ void k_const(const float* __restrict__ Win, const float* __restrict__ bin,
                        const float* __restrict__ Wout, const float* __restrict__ bout,
                        const float* __restrict__ gatW, const float* __restrict__ gal,
                        const float* __restrict__ gar, const float* __restrict__ encW,
                        const float* __restrict__ encb,
                        const float* __restrict__ aW, const float* __restrict__ ab,
                        const float* __restrict__ pW, const float* __restrict__ pb,
                        float* __restrict__ cb)
{
    for (int idx = threadIdx.x; idx < 786; idx += blockDim.x) {
        float acc = 0.f;
        if (idx < 361) {                       // M[i][j] = sum_e Wq[e][i] Wk[e][j]
            int i = idx/19, j = idx%19;
            for (int e = 0; e < EDIM; ++e) acc += Win[e*EDIM+i]*Win[(EDIM+e)*EDIM+j];
        } else if (idx < 722) {                // P[i][j] = sum_e Wout[i][e] Wv[e][j]
            int k = idx-361; int i = k/19, j = k%19;
            for (int e = 0; e < EDIM; ++e) acc += Wout[i*EDIM+e]*Win[(2*EDIM+e)*EDIM+j];
        } else if (idx < 741) {                // g[j] = sum_e bq[e] Wk[e][j]
            int j = idx-722;
            for (int e = 0; e < EDIM; ++e) acc += bin[e]*Win[(EDIM+e)*EDIM+j];
        } else if (idx < 760) {                // h[i] = sum_e Wq[e][i] bk[e]
            int i = idx-741;
            for (int e = 0; e < EDIM; ++e) acc += Win[e*EDIM+i]*bin[EDIM+e];
        } else if (idx < 779) {                // r[i] = Wout bv + bout
            int i = idx-760; acc = bout[i];
            for (int e = 0; e < EDIM; ++e) acc += Wout[i*EDIM+e]*bin[2*EDIM+e];
        } else if (idx == 779) {               // c0 = bq.bk
            for (int e = 0; e < EDIM; ++e) acc += bin[e]*bin[EDIM+e];
        } else {                               // Wal/War
            int c = idx-780; int cc = c%3; bool left = c<3;
            for (int f2 = 0; f2 < GOUT; ++f2)
                acc += gatW[cc*GOUT+f2]*(left ? gal[f2] : gar[f2]);
        }
        cb[idx] = acc;
    }
    // cbig[g]: folded head biases. g = host*11 + jj; jj=0 anomaly diff, jj>=1 proto jj-1
    for (int g = threadIdx.x; g < 176; g += blockDim.x) {
        int host = g / 11, jj = g % 11;
        float acc = (jj == 0) ? (ab[0] - ab[1]) : pb[jj-1];
        for (int l = 0; l < NLAT; ++l) {
            float coef = (jj == 0) ? (aW[l] - aW[NLAT+l]) : pW[(jj-1)*NLAT + l];
            acc += coef * encb[host*NLAT + l];
        }
        cb[CB_CBIG + g] = acc;
    }
    // B-frags of Wbig^T [K=64 x N=176] bf16, mfma_16x16x32 layout:
    //  ushort u = ((half*11+n)*64 + lane)*8 + j ;  k = half*32+(lane>>4)*8+j ; g = n*16+(lane&15)
    unsigned short* bf = (unsigned short*)(cb + CB_BF);
    for (int u = threadIdx.x; u < 11264; u += blockDim.x) {
        int j    = u & 7;
        int lane = (u >> 3) & 63;
        int tile = u >> 9;              // 0..21
        int half = tile / 11, n = tile % 11;
        int k = half*32 + ((lane >> 4) & 3)*8 + j;
        int g = n*16 + (lane & 15);
        float acc = 0.f;
        if (k < 57) {
            int host = g / 11, jj = g % 11;
            for (int l = 0; l < NLAT; ++l) {
                float coef = (jj == 0) ? (aW[l] - aW[NLAT+l]) : pW[(jj-1)*NLAT + l];
                acc += coef * encW[(host*NLAT + l)*57 + k];
            }
        }
        bf[u] = f2bf(acc);
    }
}

// ---------------- K1: per-(b,w) GRU-gi + GAT -> ws1[25 streams][B] ----------------
__global__ __launch_bounds__(256) void k_front(
    const float* __restrict__ t, const float* __restrict__ Wih, const float* __restrict__ bih,
    const float* __restrict__ gatW, const float* __restrict__ cb,
    float* __restrict__ ws1, int B)
{
    const int b = blockIdx.x*blockDim.x + threadIdx.x;
    const int w = blockIdx.y;
    if (b >= B) return;

    float x[NF];
    const float* tp = t + ((size_t)b*NW + w)*NF;
#pragma unroll
    for (int i = 0; i < NF/4; ++i) {
        float4 v = *reinterpret_cast<const float4*>(tp + i*4);
        x[i*4+0]=v.x; x[i*4+1]=v.y; x[i*4+2]=v.z; x[i*4+3]=v.w;
    }
    float* o = ws1 + (size_t)w*25*B + b;       // stream k lives at o[k*B]
    // gi = Wih x + bih
#pragma unroll
    for (int r = 0; r < 9; ++r) {
        float acc = bih[r];
#pragma unroll
        for (int j = 0; j < NF; ++j) acc += x[j]*Wih[r*NF+j];
        o[(size_t)r*B] = acc;
    }
    // GAT (collapsed)
    const float Wal0=cb[CB_WAL],Wal1=cb[CB_WAL+1],Wal2=cb[CB_WAL+2];
    const float War0=cb[CB_WAR],War1=cb[CB_WAR+1],War2=cb[CB_WAR+2];
    float el[NHOST], er[NHOST];
#pragma unroll
    for (int n = 0; n < NHOST; ++n) {
        el[n] = x[n*3+0]*Wal0 + x[n*3+1]*Wal1 + x[n*3+2]*Wal2;
        er[n] = x[n*3+0]*War0 + x[n*3+1]*War1 + x[n*3+2]*War2;
    }
    float beta[NHOST];
#pragma unroll
    for (int u = 0; u < NHOST; ++u) beta[u] = 0.f;
#pragma unroll
    for (int v = 0; v < NHOST; ++v) {
        float ee[NHOST]; float sum = 0.f;
#pragma unroll
        for (int u = 0; u < NHOST; ++u) {
            float s = er[v] + el[u];
            s = fmaxf(s, 0.2f*s);
            ee[u] = __expf(s); sum += ee[u];
        }
        float inv = frcp(sum);
#pragma unroll
        for (int u = 0; u < NHOST; ++u) beta[u] += ee[u]*inv;
    }
    float g0=0.f, g1=0.f, g2=0.f;
#pragma unroll
    for (int u = 0; u < NHOST; ++u) {
        float bu = beta[u]*(1.f/16.f);
        g0 += bu*x[u*3+0]; g1 += bu*x[u*3+1]; g2 += bu*x[u*3+2];
    }
#pragma unroll
    for (int f2 = 0; f2 < GOUT; ++f2)
        o[(size_t)(9+f2)*B] = g0*gatW[f2] + g1*gatW[GOUT+f2] + g2*gatW[2*GOUT+f2];
}

// ---------------- K2: per-b GRU chain + folded MHA -> ws2bf[64][B] bf16 ----------------
__global__ __attribute__((amdgpu_flat_work_group_size(256,256), amdgpu_waves_per_eu(1,1)))
void k_mid(const float* __restrict__ ws1, const float* __restrict__ h0,
           const float* __restrict__ Whh, const float* __restrict__ bhh,
           const float* __restrict__ cb, unsigned short* __restrict__ ws2bf, int B)
{
    const int b = blockIdx.x*blockDim.x + threadIdx.x;
    if (b >= B) return;

    float h[3] = { h0[b*3+0], h0[b*3+1], h0[b*3+2] };
    float cw[NW][EDIM];
#pragma unroll
    for (int w = 0; w < NW; ++w) {
        const float* i1 = ws1 + (size_t)w*25*B + b;
        float gi[9];
#pragma unroll
        for (int r = 0; r < 9; ++r) gi[r] = i1[(size_t)r*B];
        float gh[9];
#pragma unroll
        for (int r = 0; r < 9; ++r)
            gh[r] = bhh[r] + h[0]*Whh[r*3+0] + h[1]*Whh[r*3+1] + h[2]*Whh[r*3+2];
#pragma unroll
        for (int j = 0; j < 3; ++j) {
            float rg = fsig(gi[j]   + gh[j]);
            float zg = fsig(gi[3+j] + gh[3+j]);
            float ng = ftanh(gi[6+j] + rg*gh[6+j]);
            h[j] = (1.f - zg)*ng + zg*h[j];
        }
        cw[w][0]=h[0]; cw[w][1]=h[1]; cw[w][2]=h[2];
#pragma unroll
        for (int f2 = 0; f2 < GOUT; ++f2) cw[w][3+f2] = i1[(size_t)(9+f2)*B];
    }
    // scores_st = (cs.M.ct + g.ct + h.cs + c0)/sqrt(E)
    float hs[NW];
#pragma unroll
    for (int s = 0; s < NW; ++s) {
        float a = 0.f;
#pragma unroll
        for (int i = 0; i < EDIM; ++i) a += cw[s][i]*cb[CB_H+i];
        hs[s] = a;
    }
    const float c0 = cb[CB_C0];
    float sc[NW][NW];
#pragma unroll
    for (int tt = 0; tt < NW; ++tt) {
        float mt[EDIM];
#pragma unroll
        for (int i = 0; i < EDIM; ++i) {
            float a = 0.f;
#pragma unroll
            for (int j = 0; j < EDIM; ++j) a += cb[CB_M+i*EDIM+j]*cw[tt][j];
            mt[i] = a;
        }
        float gt = 0.f;
#pragma unroll
        for (int j = 0; j < EDIM; ++j) gt += cb[CB_G+j]*cw[tt][j];
#pragma unroll
        for (int s = 0; s < NW; ++s) {
            float a = 0.f;
#pragma unroll
            for (int i = 0; i < EDIM; ++i) a += cw[s][i]*mt[i];
            sc[s][tt] = (a + gt + hs[s] + c0) * 0.2294157338705618f;
        }
    }
    float attw[NW][NW];
#pragma unroll
    for (int s = 0; s < NW; ++s) {
        float m = fmaxf(sc[s][0], fmaxf(sc[s][1], sc[s][2]));
        float e0=__expf(sc[s][0]-m), e1=__expf(sc[s][1]-m), e2=__expf(sc[s][2]-m);
        float inv = frcp(e0+e1+e2);
        attw[s][0]=e0*inv; attw[s][1]=e1*inv; attw[s][2]=e2*inv;
    }
    // f_s = sum_t attw_st * (P ct) + r
    float fac[NW][EDIM];
#pragma unroll
    for (int s = 0; s < NW; ++s)
#pragma unroll
        for (int i = 0; i < EDIM; ++i) fac[s][i] = cb[CB_R+i];
#pragma unroll
    for (int tt = 0; tt < NW; ++tt) {
        float pc[EDIM];
#pragma unroll
        for (int i = 0; i < EDIM; ++i) {
            float a = 0.f;
#pragma unroll
            for (int j = 0; j < EDIM; ++j) a += cb[CB_P+i*EDIM+j]*cw[tt][j];
            pc[i] = a;
        }
#pragma unroll
        for (int s = 0; s < NW; ++s)
#pragma unroll
            for (int i = 0; i < EDIM; ++i) fac[s][i] += attw[s][tt]*pc[i];
    }
    // store bf16 rows 0..56, zero-pad rows 57..63 (MFMA K=64)
#pragma unroll
    for (int s = 0; s < NW; ++s)
#pragma unroll
        for (int i = 0; i < EDIM; ++i)
            ws2bf[(size_t)(s*EDIM+i)*B + b] = f2bf(fac[s][i]);
#pragma unroll
    for (int r = 57; r < 64; ++r) ws2bf[(size_t)r*B + b] = 0;
}

// ---------------- K3: encoder+heads GEMM via MFMA ----------------
// Wave = 16 b's. Per N-tile (11 tiles of 16 logits): load prepacked B-frags,
// 2x mfma_f32_16x16x32_bf16 (K=64), write f32x4 to LDS -> acc dead per tile.
// True live set ~40 VGPR: nothing for the RA to spill.
// Then thread=(b,host): 11 LDS logits + folded bias + sigmoid -> float2 stores.
__global__ __launch_bounds__(256) void k_enc(
    const unsigned short* __restrict__ ws2bf, const float* __restrict__ cb,
    float* __restrict__ outA, float* __restrict__ outP, int B)
{
    __shared__ float lg[64][178];              // 64 b's x 176 logits (+2 pad)
    const int lane = threadIdx.x & 63;
    const int wv   = __builtin_amdgcn_readfirstlane(threadIdx.x >> 6);
    const int b0   = blockIdx.x*64;
    if (b0 >= B) return;

    // A-frags: brow = b0 + wv*16 + (lane&15), k = half*32 + (lane>>4)*8 + j
    const int brow = b0 + wv*16 + (lane & 15);
    const int koff = (lane >> 4) * 8;
    union { bf16x8 v; unsigned short s[8]; } a0, a1;
#pragma unroll
    for (int j = 0; j < 8; ++j) {
        a0.s[j] = ws2bf[(size_t)(koff + j)*B + brow];
        a1.s[j] = ws2bf[(size_t)(32 + koff + j)*B + brow];
    }

    const uint4* bfq = (const uint4*)(cb + CB_BF);   // frag (tile) -> uint4 per lane
    const int r0 = wv*16 + ((lane >> 4) << 2);       // LDS row base for this lane's acc
#pragma unroll
    for (int n = 0; n < 11; ++n) {
        union { uint4 q; bf16x8 v; } bf0, bf1;
        bf0.q = bfq[(size_t)n*64 + lane];            // half 0
        bf1.q = bfq[(size_t)(11 + n)*64 + lane];     // half 1
        f32x4 acc = {0.f, 0.f, 0.f, 0.f};
        acc = __builtin_amdgcn_mfma_f32_16x16x32_bf16(a0.v, bf0.v, acc, 0, 0, 0);
        acc = __builtin_amdgcn_mfma_f32_16x16x32_bf16(a1.v, bf1.v, acc, 0, 0, 0);
        const int c = n*16 + (lane & 15);
#pragma unroll
        for (int r = 0; r < 4; ++r) lg[r0 + r][c] = acc[r];
    }
    __syncthreads();

    // heads: thread covers host=(tid&15), 4 b's
    const int host = threadIdx.x & 15;
    const int tg   = threadIdx.x >> 4;               // 0..15
    const float* cbig = cb + CB_CBIG;
#pragma unroll
    for (int i = 0; i < 4; ++i) {
        const int bl = tg + 16*i;
        const int b  = b0 + bl;
        float v[11];
#pragma unroll
        for (int jj = 0; jj < 11; ++jj)
            v[jj] = lg[bl][host*11 + jj] + cbig[host*11 + jj];
        float p0 = fsig(v[0]);
        float2 av; av.x = p0; av.y = 1.f - p0;
        *reinterpret_cast<float2*>(outA + (size_t)b*32 + host*2) = av;
        float* pP = outP + (size_t)b*160 + host*10;
#pragma unroll
        for (int p = 0; p < 5; ++p) {
            float2 pv; pv.x = fsig(v[1 + 2*p]); pv.y = fsig(v[2 + 2*p]);
            *reinterpret_cast<float2*>(pP + 2*p) = pv;
        }
    }
}

extern "C" void kernel_launch(void* const* d_in, const int* in_sizes, int n_in,
                              void* d_out, int out_size, void* d_ws, size_t ws_size,
                              hipStream_t stream) {
    const float* t    = (const float*)d_in[0];
    const float* h0   = (const float*)d_in[2];
    const float* Wih  = (const float*)d_in[3];
    const float* Whh  = (const float*)d_in[4];
    const float* bih  = (const float*)d_in[5];
    const float* bhh  = (const float*)d_in[6];
    const float* gatW = (const float*)d_in[7];
    const float* gal  = (const float*)d_in[8];
    const float* gar  = (const float*)d_in[9];
    const float* Win  = (const float*)d_in[10];
    const float* bin  = (const float*)d_in[11];
    const float* Wout = (const float*)d_in[12];
    const float* bout = (const float*)d_in[13];
    const float* encW = (const float*)d_in[14];
    const float* encb = (const float*)d_in[15];
    const float* aW   = (const float*)d_in[16];
    const float* ab   = (const float*)d_in[17];
    const float* pW   = (const float*)d_in[18];
    const float* pb   = (const float*)d_in[19];

    const int B = in_sizes[0] / (NW * NF);
    float* cb  = (float*)d_ws;
    float* ws1 = cb + CB_TOT;
    unsigned short* ws2bf = (unsigned short*)(ws1 + (size_t)25*NW*B);
    float* outA = (float*)d_out;
    float* outP = (float*)d_out + (size_t)B*32;

    k_const<<<1, 512, 0, stream>>>(Win, bin, Wout, bout, gatW, gal, gar,
                                   encW, encb, aW, ab, pW, pb, cb);
    k_front<<<dim3((B+255)/256, NW), 256, 0, stream>>>(t, Wih, bih, gatW, cb, ws1, B);
    k_mid<<<dim3((B+255)/256), 256, 0, stream>>>(ws1, h0, Whh, bhh, cb, ws2bf, B);
    k_enc<<<dim3((B+63)/64), 256, 0, stream>>>(ws2bf, cb, outA, outP, B);
}

// Round 9
// 77.301 us; speedup vs baseline: 3.3037x; 1.4279x over previous
//
#include <hip/hip_runtime.h>

#define NW 3
#define NF 48
#define NHOST 16
#define NLAT 10
#define GOUT 16
#define EDIM 19
#define PDIM 10

// const-buffer layout (floats)
#define CB_M    0     // 19x19  Wq^T Wk
#define CB_P    361   // 19x19  Wout Wv
#define CB_G    722   // 19     bq^T Wk
#define CB_H    741   // 19     Wq^T bk
#define CB_R    760   // 19     Wout bv + bout
#define CB_C0   779   // 1      bq.bk
#define CB_WAL  780   // 3      gatW @ gal
#define CB_WAR  783   // 3      gatW @ gar
#define CB_CBIG 800   // 176    folded head biases (g = host*11 + {diff,p0..p9})
#define CB_BF   976   // 11264 ushorts (5632 floats): B-frags of Wbig^T, bf16
#define CB_TOT  10240

typedef __attribute__((ext_vector_type(8))) short bf16x8;
typedef __attribute__((ext_vector_type(4))) float f32x4;

__device__ __forceinline__ float frcp(float x){ return __builtin_amdgcn_rcpf(x); }
__device__ __forceinline__ float fsig(float x){ return frcp(1.f + __expf(-x)); }
__device__ __forceinline__ float ftanh(float x){ return 1.f - 2.f*frcp(1.f + __expf(2.f*x)); }
__device__ __forceinline__ unsigned short f2bf(float x){
    union { float f; unsigned u; } v; v.f = x;
    unsigned r = v.u + 0x7FFFu + ((v.u >> 16) & 1u);
    return (unsigned short)(r >> 16);
}

// ---------------- K0: fold weights; grid-parallel (R8: 1 block = 51us serial) ----------------
// work items: [0,786) MHA folds | [786,962) cbig | [962,12226) B-frags
__global__ __launch_bounds__(256) void k_const(
    const float* __restrict__ Win, const float* __restrict__ bin,
    const float* __restrict__ Wout, const float* __restrict__ bout,
    const float* __restrict__ gatW, const float* __restrict__ gal,
    const float* __restrict__ gar, const float* __restrict__ encW,
    const float* __restrict__ encb,
    const float* __restrict__ aW, const float* __restrict__ ab,
    const float* __restrict__ pW, const float* __restrict__ pb,
    float* __restrict__ cb)
{
    const int w = blockIdx.x*blockDim.x + threadIdx.x;
    if (w < 786) {
        const int idx = w;
        float acc = 0.f;
        if (idx < 361) {                       // M[i][j] = sum_e Wq[e][i] Wk[e][j]
            int i = idx/19, j = idx%19;
            for (int e = 0; e < EDIM; ++e) acc += Win[e*EDIM+i]*Win[(EDIM+e)*EDIM+j];
        } else if (idx < 722) {                // P[i][j] = sum_e Wout[i][e] Wv[e][j]
            int k = idx-361; int i = k/19, j = k%19;
            for (int e = 0; e < EDIM; ++e) acc += Wout[i*EDIM+e]*Win[(2*EDIM+e)*EDIM+j];
        } else if (idx < 741) {                // g[j] = sum_e bq[e] Wk[e][j]
            int j = idx-722;
            for (int e = 0; e < EDIM; ++e) acc += bin[e]*Win[(EDIM+e)*EDIM+j];
        } else if (idx < 760) {                // h[i] = sum_e Wq[e][i] bk[e]
            int i = idx-741;
            for (int e = 0; e < EDIM; ++e) acc += Win[e*EDIM+i]*bin[EDIM+e];
        } else if (idx < 779) {                // r[i] = Wout bv + bout
            int i = idx-760; acc = bout[i];
            for (int e = 0; e < EDIM; ++e) acc += Wout[i*EDIM+e]*bin[2*EDIM+e];
        } else if (idx == 779) {               // c0 = bq.bk
            for (int e = 0; e < EDIM; ++e) acc += bin[e]*bin[EDIM+e];
        } else {                               // Wal/War
            int c = idx-780; int cc = c%3; bool left = c<3;
            for (int f2 = 0; f2 < GOUT; ++f2)
                acc += gatW[cc*GOUT+f2]*(left ? gal[f2] : gar[f2]);
        }
        cb[idx] = acc;
    } else if (w < 962) {
        // cbig[g]: folded head biases. g = host*11 + jj; jj=0 anomaly diff, jj>=1 proto jj-1
        const int g = w - 786;
        int host = g / 11, jj = g % 11;
        float acc = (jj == 0) ? (ab[0] - ab[1]) : pb[jj-1];
        for (int l = 0; l < NLAT; ++l) {
            float coef = (jj == 0) ? (aW[l] - aW[NLAT+l]) : pW[(jj-1)*NLAT + l];
            acc += coef * encb[host*NLAT + l];
        }
        cb[CB_CBIG + g] = acc;
    } else if (w < 12226) {
        // B-frags of Wbig^T [K=64 x N=176] bf16, mfma_16x16x32 layout:
        //  u = ((half*11+n)*64 + lane)*8 + j ; k = half*32+(lane>>4)*8+j ; g = n*16+(lane&15)
        unsigned short* bf = (unsigned short*)(cb + CB_BF);
        const int u = w - 962;
        int j    = u & 7;
        int lane = (u >> 3) & 63;
        int tile = u >> 9;              // 0..21
        int half = tile / 11, n = tile % 11;
        int k = half*32 + ((lane >> 4) & 3)*8 + j;
        int g = n*16 + (lane & 15);
        float acc = 0.f;
        if (k < 57) {
            int host = g / 11, jj = g % 11;
            for (int l = 0; l < NLAT; ++l) {
                float coef = (jj == 0) ? (aW[l] - aW[NLAT+l]) : pW[(jj-1)*NLAT + l];
                acc += coef * encW[(host*NLAT + l)*57 + k];
            }
        }
        bf[u] = f2bf(acc);
    }
}

// ---------------- K1: per-(b,w) GRU-gi + GAT -> ws1[25 streams][B] ----------------
__global__ __launch_bounds__(256) void k_front(
    const float* __restrict__ t, const float* __restrict__ Wih, const float* __restrict__ bih,
    const float* __restrict__ gatW, const float* __restrict__ cb,
    float* __restrict__ ws1, int B)
{
    const int b = blockIdx.x*blockDim.x + threadIdx.x;
    const int w = blockIdx.y;
    if (b >= B) return;

    float x[NF];
    const float* tp = t + ((size_t)b*NW + w)*NF;
#pragma unroll
    for (int i = 0; i < NF/4; ++i) {
        float4 v = *reinterpret_cast<const float4*>(tp + i*4);
        x[i*4+0]=v.x; x[i*4+1]=v.y; x[i*4+2]=v.z; x[i*4+3]=v.w;
    }
    float* o = ws1 + (size_t)w*25*B + b;       // stream k lives at o[k*B]
    // gi = Wih x + bih
#pragma unroll
    for (int r = 0; r < 9; ++r) {
        float acc = bih[r];
#pragma unroll
        for (int j = 0; j < NF; ++j) acc += x[j]*Wih[r*NF+j];
        o[(size_t)r*B] = acc;
    }
    // GAT (collapsed)
    const float Wal0=cb[CB_WAL],Wal1=cb[CB_WAL+1],Wal2=cb[CB_WAL+2];
    const float War0=cb[CB_WAR],War1=cb[CB_WAR+1],War2=cb[CB_WAR+2];
    float el[NHOST], er[NHOST];
#pragma unroll
    for (int n = 0; n < NHOST; ++n) {
        el[n] = x[n*3+0]*Wal0 + x[n*3+1]*Wal1 + x[n*3+2]*Wal2;
        er[n] = x[n*3+0]*War0 + x[n*3+1]*War1 + x[n*3+2]*War2;
    }
    float beta[NHOST];
#pragma unroll
    for (int u = 0; u < NHOST; ++u) beta[u] = 0.f;
#pragma unroll
    for (int v = 0; v < NHOST; ++v) {
        float ee[NHOST]; float sum = 0.f;
#pragma unroll
        for (int u = 0; u < NHOST; ++u) {
            float s = er[v] + el[u];
            s = fmaxf(s, 0.2f*s);
            ee[u] = __expf(s); sum += ee[u];
        }
        float inv = frcp(sum);
#pragma unroll
        for (int u = 0; u < NHOST; ++u) beta[u] += ee[u]*inv;
    }
    float g0=0.f, g1=0.f, g2=0.f;
#pragma unroll
    for (int u = 0; u < NHOST; ++u) {
        float bu = beta[u]*(1.f/16.f);
        g0 += bu*x[u*3+0]; g1 += bu*x[u*3+1]; g2 += bu*x[u*3+2];
    }
#pragma unroll
    for (int f2 = 0; f2 < GOUT; ++f2)
        o[(size_t)(9+f2)*B] = g0*gatW[f2] + g1*gatW[GOUT+f2] + g2*gatW[2*GOUT+f2];
}

// ---------------- K2: per-b GRU chain + folded MHA -> ws2bf[64][B] bf16 ----------------
__global__ __attribute__((amdgpu_flat_work_group_size(256,256), amdgpu_waves_per_eu(1,1)))
void k_mid(const float* __restrict__ ws1, const float* __restrict__ h0,
           const float* __restrict__ Whh, const float* __restrict__ bhh,
           const float* __restrict__ cb, unsigned short* __restrict__ ws2bf, int B)
{
    const int b = blockIdx.x*blockDim.x + threadIdx.x;
    if (b >= B) return;

    float h[3] = { h0[b*3+0], h0[b*3+1], h0[b*3+2] };
    float cw[NW][EDIM];
#pragma unroll
    for (int w = 0; w < NW; ++w) {
        const float* i1 = ws1 + (size_t)w*25*B + b;
        float gi[9];
#pragma unroll
        for (int r = 0; r < 9; ++r) gi[r] = i1[(size_t)r*B];
        float gh[9];
#pragma unroll
        for (int r = 0; r < 9; ++r)
            gh[r] = bhh[r] + h[0]*Whh[r*3+0] + h[1]*Whh[r*3+1] + h[2]*Whh[r*3+2];
#pragma unroll
        for (int j = 0; j < 3; ++j) {
            float rg = fsig(gi[j]   + gh[j]);
            float zg = fsig(gi[3+j] + gh[3+j]);
            float ng = ftanh(gi[6+j] + rg*gh[6+j]);
            h[j] = (1.f - zg)*ng + zg*h[j];
        }
        cw[w][0]=h[0]; cw[w][1]=h[1]; cw[w][2]=h[2];
#pragma unroll
        for (int f2 = 0; f2 < GOUT; ++f2) cw[w][3+f2] = i1[(size_t)(9+f2)*B];
    }
    // scores_st = (cs.M.ct + g.ct + h.cs + c0)/sqrt(E)
    float hs[NW];
#pragma unroll
    for (int s = 0; s < NW; ++s) {
        float a = 0.f;
#pragma unroll
        for (int i = 0; i < EDIM; ++i) a += cw[s][i]*cb[CB_H+i];
        hs[s] = a;
    }
    const float c0 = cb[CB_C0];
    float sc[NW][NW];
#pragma unroll
    for (int tt = 0; tt < NW; ++tt) {
        float mt[EDIM];
#pragma unroll
        for (int i = 0; i < EDIM; ++i) {
            float a = 0.f;
#pragma unroll
            for (int j = 0; j < EDIM; ++j) a += cb[CB_M+i*EDIM+j]*cw[tt][j];
            mt[i] = a;
        }
        float gt = 0.f;
#pragma unroll
        for (int j = 0; j < EDIM; ++j) gt += cb[CB_G+j]*cw[tt][j];
#pragma unroll
        for (int s = 0; s < NW; ++s) {
            float a = 0.f;
#pragma unroll
            for (int i = 0; i < EDIM; ++i) a += cw[s][i]*mt[i];
            sc[s][tt] = (a + gt + hs[s] + c0) * 0.2294157338705618f;
        }
    }
    float attw[NW][NW];
#pragma unroll
    for (int s = 0; s < NW; ++s) {
        float m = fmaxf(sc[s][0], fmaxf(sc[s][1], sc[s][2]));
        float e0=__expf(sc[s][0]-m), e1=__expf(sc[s][1]-m), e2=__expf(sc[s][2]-m);
        float inv = frcp(e0+e1+e2);
        attw[s][0]=e0*inv; attw[s][1]=e1*inv; attw[s][2]=e2*inv;
    }
    // f_s = sum_t attw_st * (P ct) + r
    float fac[NW][EDIM];
#pragma unroll
    for (int s = 0; s < NW; ++s)
#pragma unroll
        for (int i = 0; i < EDIM; ++i) fac[s][i] = cb[CB_R+i];
#pragma unroll
    for (int tt = 0; tt < NW; ++tt) {
        float pc[EDIM];
#pragma unroll
        for (int i = 0; i < EDIM; ++i) {
            float a = 0.f;
#pragma unroll
            for (int j = 0; j < EDIM; ++j) a += cb[CB_P+i*EDIM+j]*cw[tt][j];
            pc[i] = a;
        }
#pragma unroll
        for (int s = 0; s < NW; ++s)
#pragma unroll
            for (int i = 0; i < EDIM; ++i) fac[s][i] += attw[s][tt]*pc[i];
    }
    // store bf16 rows 0..56, zero-pad rows 57..63 (MFMA K=64)
#pragma unroll
    for (int s = 0; s < NW; ++s)
#pragma unroll
        for (int i = 0; i < EDIM; ++i)
            ws2bf[(size_t)(s*EDIM+i)*B + b] = f2bf(fac[s][i]);
#pragma unroll
    for (int r = 57; r < 64; ++r) ws2bf[(size_t)r*B + b] = 0;
}

// ---------------- K3: encoder+heads GEMM via MFMA ----------------
__global__ __launch_bounds__(256) void k_enc(
    const unsigned short* __restrict__ ws2bf, const float* __restrict__ cb,
    float* __restrict__ outA, float* __restrict__ outP, int B)
{
    __shared__ float lg[64][178];              // 64 b's x 176 logits (+2 pad)
    const int lane = threadIdx.x & 63;
    const int wv   = __builtin_amdgcn_readfirstlane(threadIdx.x >> 6);
    const int b0   = blockIdx.x*64;
    if (b0 >= B) return;

    // A-frags: brow = b0 + wv*16 + (lane&15), k = half*32 + (lane>>4)*8 + j
    const int brow = b0 + wv*16 + (lane & 15);
    const int koff = (lane >> 4) * 8;
    union { bf16x8 v; unsigned short s[8]; } a0, a1;
#pragma unroll
    for (int j = 0; j < 8; ++j) {
        a0.s[j] = ws2bf[(size_t)(koff + j)*B + brow];
        a1.s[j] = ws2bf[(size_t)(32 + koff + j)*B + brow];
    }

    const uint4* bfq = (const uint4*)(cb + CB_BF);   // frag (tile) -> uint4 per lane
    const int r0 = wv*16 + ((lane >> 4) << 2);       // LDS row base for this lane's acc
#pragma unroll
    for (int n = 0; n < 11; ++n) {
        union { uint4 q; bf16x8 v; } bf0, bf1;
        bf0.q = bfq[(size_t)n*64 + lane];            // half 0
        bf1.q = bfq[(size_t)(11 + n)*64 + lane];     // half 1
        f32x4 acc = {0.f, 0.f, 0.f, 0.f};
        acc = __builtin_amdgcn_mfma_f32_16x16x32_bf16(a0.v, bf0.v, acc, 0, 0, 0);
        acc = __builtin_amdgcn_mfma_f32_16x16x32_bf16(a1.v, bf1.v, acc, 0, 0, 0);
        const int c = n*16 + (lane & 15);
#pragma unroll
        for (int r = 0; r < 4; ++r) lg[r0 + r][c] = acc[r];
    }
    __syncthreads();

    // heads: thread covers host=(tid&15), 4 b's
    const int host = threadIdx.x & 15;
    const int tg   = threadIdx.x >> 4;               // 0..15
    const float* cbig = cb + CB_CBIG;
#pragma unroll
    for (int i = 0; i < 4; ++i) {
        const int bl = tg + 16*i;
        const int b  = b0 + bl;
        float v[11];
#pragma unroll
        for (int jj = 0; jj < 11; ++jj)
            v[jj] = lg[bl][host*11 + jj] + cbig[host*11 + jj];
        float p0 = fsig(v[0]);
        float2 av; av.x = p0; av.y = 1.f - p0;
        *reinterpret_cast<float2*>(outA + (size_t)b*32 + host*2) = av;
        float* pP = outP + (size_t)b*160 + host*10;
#pragma unroll
        for (int p = 0; p < 5; ++p) {
            float2 pv; pv.x = fsig(v[1 + 2*p]); pv.y = fsig(v[2 + 2*p]);
            *reinterpret_cast<float2*>(pP + 2*p) = pv;
        }
    }
}

extern "C" void kernel_launch(void* const* d_in, const int* in_sizes, int n_in,
                              void* d_out, int out_size, void* d_ws, size_t ws_size,
                              hipStream_t stream) {
    const float* t    = (const float*)d_in[0];
    const float* h0   = (const float*)d_in[2];
    const float* Wih  = (const float*)d_in[3];
    const float* Whh  = (const float*)d_in[4];
    const float* bih  = (const float*)d_in[5];
    const float* bhh  = (const float*)d_in[6];
    const float* gatW = (const float*)d_in[7];
    const float* gal  = (const float*)d_in[8];
    const float* gar  = (const float*)d_in[9];
    const float* Win  = (const float*)d_in[10];
    const float* bin  = (const float*)d_in[11];
    const float* Wout = (const float*)d_in[12];
    const float* bout = (const float*)d_in[13];
    const float* encW = (const float*)d_in[14];
    const float* encb = (const float*)d_in[15];
    const float* aW   = (const float*)d_in[16];
    const float* ab   = (const float*)d_in[17];
    const float* pW   = (const float*)d_in[18];
    const float* pb   = (const float*)d_in[19];

    const int B = in_sizes[0] / (NW * NF);
    float* cb  = (float*)d_ws;
    float* ws1 = cb + CB_TOT;
    unsigned short* ws2bf = (unsigned short*)(ws1 + (size_t)25*NW*B);
    float* outA = (float*)d_out;
    float* outP = (float*)d_out + (size_t)B*32;

    k_const<<<dim3(48), 256, 0, stream>>>(Win, bin, Wout, bout, gatW, gal, gar,
                                          encW, encb, aW, ab, pW, pb, cb);
    k_front<<<dim3((B+255)/256, NW), 256, 0, stream>>>(t, Wih, bih, gatW, cb, ws1, B);
    k_mid<<<dim3((B+255)/256), 256, 0, stream>>>(ws1, h0, Whh, bhh, cb, ws2bf, B);
    k_enc<<<dim3((B+63)/64), 256, 0, stream>>>(ws2bf, cb, outA, outP, B);
}

// Round 10
// 77.234 us; speedup vs baseline: 3.3066x; 1.0009x over previous
//
#include <hip/hip_runtime.h>

#define NW 3
#define NF 48
#define NHOST 16
#define NLAT 10
#define GOUT 16
#define EDIM 19
#define PDIM 10

// const-buffer layout (floats)
#define CB_M    0     // 19x19  Wq^T Wk
#define CB_P    361   // 19x19  Wout Wv
#define CB_G    722   // 19     bq^T Wk
#define CB_H    741   // 19     Wq^T bk
#define CB_R    760   // 19     Wout bv + bout
#define CB_C0   779   // 1      bq.bk
#define CB_WAL  780   // 3      gatW @ gal
#define CB_WAR  783   // 3      gatW @ gar
#define CB_CBIG 800   // 176    folded head biases (g = host*11 + {diff,p0..p9})
#define CB_BF   976   // 11264 ushorts (5632 floats): B-frags of Wbig^T, bf16
#define CB_TOT  10240

typedef __attribute__((ext_vector_type(8))) short bf16x8;
typedef __attribute__((ext_vector_type(4))) float f32x4;

__device__ __forceinline__ float frcp(float x){ return __builtin_amdgcn_rcpf(x); }
__device__ __forceinline__ float fsig(float x){ return frcp(1.f + __expf(-x)); }
__device__ __forceinline__ float ftanh(float x){ return 1.f - 2.f*frcp(1.f + __expf(2.f*x)); }
__device__ __forceinline__ unsigned short f2bf(float x){
    union { float f; unsigned u; } v; v.f = x;
    unsigned r = v.u + 0x7FFFu + ((v.u >> 16) & 1u);
    return (unsigned short)(r >> 16);
}

// ---------------- K0: fold weights; grid-parallel ----------------
// work items: [0,786) MHA folds | [786,962) cbig | [962,12226) B-frags
__global__ __launch_bounds__(256) void k_const(
    const float* __restrict__ Win, const float* __restrict__ bin,
    const float* __restrict__ Wout, const float* __restrict__ bout,
    const float* __restrict__ gatW, const float* __restrict__ gal,
    const float* __restrict__ gar, const float* __restrict__ encW,
    const float* __restrict__ encb,
    const float* __restrict__ aW, const float* __restrict__ ab,
    const float* __restrict__ pW, const float* __restrict__ pb,
    float* __restrict__ cb)
{
    const int w = blockIdx.x*blockDim.x + threadIdx.x;
    if (w < 786) {
        const int idx = w;
        float acc = 0.f;
        if (idx < 361) {                       // M[i][j] = sum_e Wq[e][i] Wk[e][j]
            int i = idx/19, j = idx%19;
            for (int e = 0; e < EDIM; ++e) acc += Win[e*EDIM+i]*Win[(EDIM+e)*EDIM+j];
        } else if (idx < 722) {                // P[i][j] = sum_e Wout[i][e] Wv[e][j]
            int k = idx-361; int i = k/19, j = k%19;
            for (int e = 0; e < EDIM; ++e) acc += Wout[i*EDIM+e]*Win[(2*EDIM+e)*EDIM+j];
        } else if (idx < 741) {                // g[j] = sum_e bq[e] Wk[e][j]
            int j = idx-722;
            for (int e = 0; e < EDIM; ++e) acc += bin[e]*Win[(EDIM+e)*EDIM+j];
        } else if (idx < 760) {                // h[i] = sum_e Wq[e][i] bk[e]
            int i = idx-741;
            for (int e = 0; e < EDIM; ++e) acc += Win[e*EDIM+i]*bin[EDIM+e];
        } else if (idx < 779) {                // r[i] = Wout bv + bout
            int i = idx-760; acc = bout[i];
            for (int e = 0; e < EDIM; ++e) acc += Wout[i*EDIM+e]*bin[2*EDIM+e];
        } else if (idx == 779) {               // c0 = bq.bk
            for (int e = 0; e < EDIM; ++e) acc += bin[e]*bin[EDIM+e];
        } else {                               // Wal/War
            int c = idx-780; int cc = c%3; bool left = c<3;
            for (int f2 = 0; f2 < GOUT; ++f2)
                acc += gatW[cc*GOUT+f2]*(left ? gal[f2] : gar[f2]);
        }
        cb[idx] = acc;
    } else if (w < 962) {
        const int g = w - 786;
        int host = g / 11, jj = g % 11;
        float acc = (jj == 0) ? (ab[0] - ab[1]) : pb[jj-1];
        for (int l = 0; l < NLAT; ++l) {
            float coef = (jj == 0) ? (aW[l] - aW[NLAT+l]) : pW[(jj-1)*NLAT + l];
            acc += coef * encb[host*NLAT + l];
        }
        cb[CB_CBIG + g] = acc;
    } else if (w < 12226) {
        // B-frags of Wbig^T [K=64 x N=176] bf16, mfma_16x16x32 layout:
        //  u = ((half*11+n)*64 + lane)*8 + j ; k = half*32+(lane>>4)*8+j ; g = n*16+(lane&15)
        unsigned short* bf = (unsigned short*)(cb + CB_BF);
        const int u = w - 962;
        int j    = u & 7;
        int lane = (u >> 3) & 63;
        int tile = u >> 9;              // 0..21
        int half = tile / 11, n = tile % 11;
        int k = half*32 + ((lane >> 4) & 3)*8 + j;
        int g = n*16 + (lane & 15);
        float acc = 0.f;
        if (k < 57) {
            int host = g / 11, jj = g % 11;
            for (int l = 0; l < NLAT; ++l) {
                float coef = (jj == 0) ? (aW[l] - aW[NLAT+l]) : pW[(jj-1)*NLAT + l];
                acc += coef * encW[(host*NLAT + l)*57 + k];
            }
        }
        bf[u] = f2bf(acc);
    }
}

// ---------------- K1: per-(b,w) GRU-gi + GAT -> ws1[25 streams][B] ----------------
__global__ __launch_bounds__(256) void k_front(
    const float* __restrict__ t, const float* __restrict__ Wih, const float* __restrict__ bih,
    const float* __restrict__ gatW, const float* __restrict__ cb,
    float* __restrict__ ws1, int B)
{
    const int b = blockIdx.x*blockDim.x + threadIdx.x;
    const int w = blockIdx.y;
    if (b >= B) return;

    float x[NF];
    const float* tp = t + ((size_t)b*NW + w)*NF;
#pragma unroll
    for (int i = 0; i < NF/4; ++i) {
        float4 v = *reinterpret_cast<const float4*>(tp + i*4);
        x[i*4+0]=v.x; x[i*4+1]=v.y; x[i*4+2]=v.z; x[i*4+3]=v.w;
    }
    float* o = ws1 + (size_t)w*25*B + b;       // stream k lives at o[k*B]
    // gi = Wih x + bih
#pragma unroll
    for (int r = 0; r < 9; ++r) {
        float acc = bih[r];
#pragma unroll
        for (int j = 0; j < NF; ++j) acc += x[j]*Wih[r*NF+j];
        o[(size_t)r*B] = acc;
    }
    // GAT (collapsed)
    const float Wal0=cb[CB_WAL],Wal1=cb[CB_WAL+1],Wal2=cb[CB_WAL+2];
    const float War0=cb[CB_WAR],War1=cb[CB_WAR+1],War2=cb[CB_WAR+2];
    float el[NHOST], er[NHOST];
#pragma unroll
    for (int n = 0; n < NHOST; ++n) {
        el[n] = x[n*3+0]*Wal0 + x[n*3+1]*Wal1 + x[n*3+2]*Wal2;
        er[n] = x[n*3+0]*War0 + x[n*3+1]*War1 + x[n*3+2]*War2;
    }
    float beta[NHOST];
#pragma unroll
    for (int u = 0; u < NHOST; ++u) beta[u] = 0.f;
#pragma unroll
    for (int v = 0; v < NHOST; ++v) {
        float ee[NHOST]; float sum = 0.f;
#pragma unroll
        for (int u = 0; u < NHOST; ++u) {
            float s = er[v] + el[u];
            s = fmaxf(s, 0.2f*s);
            ee[u] = __expf(s); sum += ee[u];
        }
        float inv = frcp(sum);
#pragma unroll
        for (int u = 0; u < NHOST; ++u) beta[u] += ee[u]*inv;
    }
    float g0=0.f, g1=0.f, g2=0.f;
#pragma unroll
    for (int u = 0; u < NHOST; ++u) {
        float bu = beta[u]*(1.f/16.f);
        g0 += bu*x[u*3+0]; g1 += bu*x[u*3+1]; g2 += bu*x[u*3+2];
    }
#pragma unroll
    for (int f2 = 0; f2 < GOUT; ++f2)
        o[(size_t)(9+f2)*B] = g0*gatW[f2] + g1*gatW[GOUT+f2] + g2*gatW[2*GOUT+f2];
}

// ---------------- K2: per-b GRU chain + folded MHA -> ws2bf[B][64] bf16 ----------------
// Live-set-reduced (R9: fac[57] eliminated): after attw, overwrite cw[tt] in
// place with PC[tt] = P@cw[tt]; outputs computed per-element during the store
// loop. Peak live ~100 floats -> no spill at the RA's budget.
__global__ __attribute__((amdgpu_flat_work_group_size(256,256), amdgpu_waves_per_eu(1,1)))
void k_mid(const float* __restrict__ ws1, const float* __restrict__ h0,
           const float* __restrict__ Whh, const float* __restrict__ bhh,
           const float* __restrict__ cb, unsigned short* __restrict__ ws2bf, int B)
{
    const int b = blockIdx.x*blockDim.x + threadIdx.x;
    if (b >= B) return;

    float h[3] = { h0[b*3+0], h0[b*3+1], h0[b*3+2] };
    float cw[57];
#pragma unroll
    for (int w = 0; w < NW; ++w) {
        const float* i1 = ws1 + (size_t)w*25*B + b;
        float gi[9];
#pragma unroll
        for (int r = 0; r < 9; ++r) gi[r] = i1[(size_t)r*B];
        float gh[9];
#pragma unroll
        for (int r = 0; r < 9; ++r)
            gh[r] = bhh[r] + h[0]*Whh[r*3+0] + h[1]*Whh[r*3+1] + h[2]*Whh[r*3+2];
#pragma unroll
        for (int j = 0; j < 3; ++j) {
            float rg = fsig(gi[j]   + gh[j]);
            float zg = fsig(gi[3+j] + gh[3+j]);
            float ng = ftanh(gi[6+j] + rg*gh[6+j]);
            h[j] = (1.f - zg)*ng + zg*h[j];
        }
        cw[w*EDIM+0]=h[0]; cw[w*EDIM+1]=h[1]; cw[w*EDIM+2]=h[2];
#pragma unroll
        for (int f2 = 0; f2 < GOUT; ++f2) cw[w*EDIM+3+f2] = i1[(size_t)(9+f2)*B];
    }
    // scores_st = (cs.M.ct + g.ct + h.cs + c0)/sqrt(E)
    float hs[NW];
#pragma unroll
    for (int s = 0; s < NW; ++s) {
        float a = 0.f;
#pragma unroll
        for (int i = 0; i < EDIM; ++i) a += cw[s*EDIM+i]*cb[CB_H+i];
        hs[s] = a;
    }
    const float c0 = cb[CB_C0];
    float sc[NW][NW];
#pragma unroll
    for (int tt = 0; tt < NW; ++tt) {
        float mt[EDIM];
#pragma unroll
        for (int i = 0; i < EDIM; ++i) {
            float a = 0.f;
#pragma unroll
            for (int j = 0; j < EDIM; ++j) a += cb[CB_M+i*EDIM+j]*cw[tt*EDIM+j];
            mt[i] = a;
        }
        float gt = 0.f;
#pragma unroll
        for (int j = 0; j < EDIM; ++j) gt += cb[CB_G+j]*cw[tt*EDIM+j];
#pragma unroll
        for (int s = 0; s < NW; ++s) {
            float a = 0.f;
#pragma unroll
            for (int i = 0; i < EDIM; ++i) a += cw[s*EDIM+i]*mt[i];
            sc[s][tt] = (a + gt + hs[s] + c0) * 0.2294157338705618f;
        }
    }
    float attw[NW][NW];
#pragma unroll
    for (int s = 0; s < NW; ++s) {
        float m = fmaxf(sc[s][0], fmaxf(sc[s][1], sc[s][2]));
        float e0=__expf(sc[s][0]-m), e1=__expf(sc[s][1]-m), e2=__expf(sc[s][2]-m);
        float inv = frcp(e0+e1+e2);
        attw[s][0]=e0*inv; attw[s][1]=e1*inv; attw[s][2]=e2*inv;
    }
    // overwrite cw[tt] <- PC[tt] = P @ cw[tt]
#pragma unroll
    for (int tt = 0; tt < NW; ++tt) {
        float pc[EDIM];
#pragma unroll
        for (int i = 0; i < EDIM; ++i) {
            float a = 0.f;
#pragma unroll
            for (int j = 0; j < EDIM; ++j) a += cb[CB_P+i*EDIM+j]*cw[tt*EDIM+j];
            pc[i] = a;
        }
#pragma unroll
        for (int i = 0; i < EDIM; ++i) cw[tt*EDIM+i] = pc[i];
    }
    // emit 64 bf16 (57 outputs + 7 zero pad) as 8x 16B chunks, b-major layout
    unsigned short* ob = ws2bf + (size_t)b*64;
#pragma unroll
    for (int c = 0; c < 8; ++c) {
        union { uint4 q; unsigned short s[8]; } pk;
#pragma unroll
        for (int e = 0; e < 8; ++e) {
            const int idx = c*8 + e;          // compile-time constant
            float val = 0.f;
            if (idx < 57) {
                const int s2 = idx / EDIM, i = idx % EDIM;
                val = cb[CB_R+i] + attw[s2][0]*cw[i] + attw[s2][1]*cw[EDIM+i]
                    + attw[s2][2]*cw[2*EDIM+i];
            }
            pk.s[e] = f2bf(val);
        }
        *reinterpret_cast<uint4*>(ob + c*8) = pk.q;
    }
}

// ---------------- K3: encoder+heads GEMM via MFMA ----------------
// ws2bf is [B][64]: A-frag = 2x dwordx4 per lane (was 16 strided ushorts).
__global__ __launch_bounds__(256) void k_enc(
    const unsigned short* __restrict__ ws2bf, const float* __restrict__ cb,
    float* __restrict__ outA, float* __restrict__ outP, int B)
{
    __shared__ float lg[64][178];              // 64 b's x 176 logits (+2 pad)
    const int lane = threadIdx.x & 63;
    const int wv   = __builtin_amdgcn_readfirstlane(threadIdx.x >> 6);
    const int b0   = blockIdx.x*64;
    if (b0 >= B) return;

    // A-frags: brow = b0 + wv*16 + (lane&15), k = half*32 + (lane>>4)*8 + j
    const int brow = b0 + wv*16 + (lane & 15);
    const int koff = (lane >> 4) * 8;
    const unsigned short* ap = ws2bf + (size_t)brow*64;
    union { uint4 q; bf16x8 v; } a0, a1;
    a0.q = *reinterpret_cast<const uint4*>(ap + koff);
    a1.q = *reinterpret_cast<const uint4*>(ap + 32 + koff);

    const uint4* bfq = (const uint4*)(cb + CB_BF);   // frag (tile) -> uint4 per lane
    const int r0 = wv*16 + ((lane >> 4) << 2);       // LDS row base for this lane's acc
#pragma unroll
    for (int n = 0; n < 11; ++n) {
        union { uint4 q; bf16x8 v; } bf0, bf1;
        bf0.q = bfq[(size_t)n*64 + lane];            // half 0
        bf1.q = bfq[(size_t)(11 + n)*64 + lane];     // half 1
        f32x4 acc = {0.f, 0.f, 0.f, 0.f};
        acc = __builtin_amdgcn_mfma_f32_16x16x32_bf16(a0.v, bf0.v, acc, 0, 0, 0);
        acc = __builtin_amdgcn_mfma_f32_16x16x32_bf16(a1.v, bf1.v, acc, 0, 0, 0);
        const int c = n*16 + (lane & 15);
#pragma unroll
        for (int r = 0; r < 4; ++r) lg[r0 + r][c] = acc[r];
    }
    __syncthreads();

    // heads: thread covers host=(tid&15), 4 b's
    const int host = threadIdx.x & 15;
    const int tg   = threadIdx.x >> 4;               // 0..15
    const float* cbig = cb + CB_CBIG;
#pragma unroll
    for (int i = 0; i < 4; ++i) {
        const int bl = tg + 16*i;
        const int b  = b0 + bl;
        float v[11];
#pragma unroll
        for (int jj = 0; jj < 11; ++jj)
            v[jj] = lg[bl][host*11 + jj] + cbig[host*11 + jj];
        float p0 = fsig(v[0]);
        float2 av; av.x = p0; av.y = 1.f - p0;
        *reinterpret_cast<float2*>(outA + (size_t)b*32 + host*2) = av;
        float* pP = outP + (size_t)b*160 + host*10;
#pragma unroll
        for (int p = 0; p < 5; ++p) {
            float2 pv; pv.x = fsig(v[1 + 2*p]); pv.y = fsig(v[2 + 2*p]);
            *reinterpret_cast<float2*>(pP + 2*p) = pv;
        }
    }
}

extern "C" void kernel_launch(void* const* d_in, const int* in_sizes, int n_in,
                              void* d_out, int out_size, void* d_ws, size_t ws_size,
                              hipStream_t stream) {
    const float* t    = (const float*)d_in[0];
    const float* h0   = (const float*)d_in[2];
    const float* Wih  = (const float*)d_in[3];
    const float* Whh  = (const float*)d_in[4];
    const float* bih  = (const float*)d_in[5];
    const float* bhh  = (const float*)d_in[6];
    const float* gatW = (const float*)d_in[7];
    const float* gal  = (const float*)d_in[8];
    const float* gar  = (const float*)d_in[9];
    const float* Win  = (const float*)d_in[10];
    const float* bin  = (const float*)d_in[11];
    const float* Wout = (const float*)d_in[12];
    const float* bout = (const float*)d_in[13];
    const float* encW = (const float*)d_in[14];
    const float* encb = (const float*)d_in[15];
    const float* aW   = (const float*)d_in[16];
    const float* ab   = (const float*)d_in[17];
    const float* pW   = (const float*)d_in[18];
    const float* pb   = (const float*)d_in[19];

    const int B = in_sizes[0] / (NW * NF);
    float* cb  = (float*)d_ws;
    float* ws1 = cb + CB_TOT;
    unsigned short* ws2bf = (unsigned short*)(ws1 + (size_t)25*NW*B);
    float* outA = (float*)d_out;
    float* outP = (float*)d_out + (size_t)B*32;

    k_const<<<dim3(48), 256, 0, stream>>>(Win, bin, Wout, bout, gatW, gal, gar,
                                          encW, encb, aW, ab, pW, pb, cb);
    k_front<<<dim3((B+255)/256, NW), 256, 0, stream>>>(t, Wih, bih, gatW, cb, ws1, B);
    k_mid<<<dim3((B+255)/256), 256, 0, stream>>>(ws1, h0, Whh, bhh, cb, ws2bf, B);
    k_enc<<<dim3((B+63)/64), 256, 0, stream>>>(ws2bf, cb, outA, outP, B);
}